// Round 16
// baseline (646.047 us; speedup 1.0000x reference)
//
#include <hip/hip_runtime.h>

#define NTX 100000
#define NUSER 20000
#define NMERCH 5000
#define HD 256
#define ROWPAD 128

using u16 = unsigned short;
typedef __attribute__((ext_vector_type(8))) short bf16x8;
typedef __attribute__((ext_vector_type(4))) float f32x4;

__device__ __forceinline__ u16 f2bf(float f){
  unsigned u = __float_as_uint(f);
  unsigned r = (u + 0x7FFFu + ((u >> 16) & 1u)) >> 16;
  return (u16)r;
}
__device__ __forceinline__ float bf2f(u16 b){
  return __uint_as_float(((unsigned)b) << 16);
}
__device__ __forceinline__ unsigned pk2(float a, float b){
  return (unsigned)f2bf(a) | ((unsigned)f2bf(b) << 16);
}

// full-row gather (8B/lane, 64 lanes per row): cooperative index load + shfl + 4 chains.
__device__ __forceinline__ void gather4(const u16* __restrict__ T, const int* __restrict__ ss,
    int j0, int j1, int lane, int c, float& o0, float& o1, float& o2, float& o3){
  float a0=0,a1=0,a2=0,a3=0, b0=0,b1=0,b2=0,b3=0;
  float c0=0,c1=0,c2=0,c3=0, d0=0,d1=0,d2=0,d3=0;
  for (int base = j0; base < j1; base += 64){
    int n = j1 - base; if (n > 64) n = 64;
    int idx = ss[base + (lane < n ? lane : 0)];
    for (int jj = 0; jj < n; jj += 4){
      int s0 = __shfl(idx, jj);
      int s1 = __shfl(idx, jj+1);
      int s2 = __shfl(idx, jj+2);
      int s3 = __shfl(idx, jj+3);
      ushort4 v0 = *(const ushort4*)(T + (size_t)s0*HD + c);
      ushort4 v1 = *(const ushort4*)(T + (size_t)s1*HD + c);
      ushort4 v2 = *(const ushort4*)(T + (size_t)s2*HD + c);
      ushort4 v3 = *(const ushort4*)(T + (size_t)s3*HD + c);
      a0 += bf2f(v0.x); a1 += bf2f(v0.y); a2 += bf2f(v0.z); a3 += bf2f(v0.w);
      if (jj+1 < n){ b0 += bf2f(v1.x); b1 += bf2f(v1.y); b2 += bf2f(v1.z); b3 += bf2f(v1.w); }
      if (jj+2 < n){ c0 += bf2f(v2.x); c1 += bf2f(v2.y); c2 += bf2f(v2.z); c3 += bf2f(v2.w); }
      if (jj+3 < n){ d0 += bf2f(v3.x); d1 += bf2f(v3.y); d2 += bf2f(v3.z); d3 += bf2f(v3.w); }
    }
  }
  o0 += (a0+b0)+(c0+d0); o1 += (a1+b1)+(c1+d1);
  o2 += (a2+b2)+(c2+d2); o3 += (a3+b3)+(c3+d3);
}

// ---------------- CSR radix-partition build (blockIdx.y = relation: 0=ut,1=tm,2=mt,3=tu) ----------------
__device__ __forceinline__ int rel_n(int y){ return y==0?NTX: y==1?NMERCH: y==2?NTX:NUSER; }
__device__ __forceinline__ int rel_coff(int y){ return y==0?0: y==1?100000: y==2?105000:205000; }
__device__ __forceinline__ int rel_rpoff(int y){ return y==0?0: y==1?100001: y==2?105002:205003; }
__device__ __forceinline__ int rel_shift(int y){ return y==0?11: y==1?8: y==2?11:10; }
__device__ __forceinline__ int rel_np(int y){ return y==0?49: y==1?20: y==2?49:20; }
#define ECH 128
#define PSTW 72

__global__ __launch_bounds__(256) void csrA_kernel(const int* __restrict__ d0p, const int* __restrict__ d1p,
    const int* __restrict__ d2p, const int* __restrict__ d3p, int nE, int* __restrict__ PC){
  int y = blockIdx.y;
  const int* dst = y==0?d0p: y==1?d1p: y==2?d2p:d3p;
  int shift = rel_shift(y);
  __shared__ int cc[64];
  int t = threadIdx.x;
  if (t < 64) cc[t] = 0;
  __syncthreads();
  int CH = (nE + ECH - 1)/ECH;
  int e0 = blockIdx.x*CH, e1 = e0 + CH; if (e1 > nE) e1 = nE;
  for (int e = e0 + t*4; e < e1; e += 1024){
    int a = dst[e];
    int b = (e+1 < e1) ? dst[e+1] : -1;
    int c = (e+2 < e1) ? dst[e+2] : -1;
    int d = (e+3 < e1) ? dst[e+3] : -1;
    atomicAdd(&cc[a>>shift], 1);
    if (b >= 0) atomicAdd(&cc[b>>shift], 1);
    if (c >= 0) atomicAdd(&cc[c>>shift], 1);
    if (d >= 0) atomicAdd(&cc[d>>shift], 1);
  }
  __syncthreads();
  if (t < 64) PC[(((size_t)y*ECH + blockIdx.x)<<6) + t] = cc[t];
}

__global__ void csrB_kernel(int* __restrict__ PC, int* __restrict__ PST, int* __restrict__ RP, int nE){
  int y = blockIdx.y;
  int np = rel_np(y);
  int t = threadIdx.x;
  __shared__ int sh[64];
  int run = 0;
  if (t < np){
    for (int c = 0; c < ECH; ++c){
      size_t idx = (((size_t)y*ECH + c)<<6) + t;
      int v = PC[idx]; PC[idx] = run; run += v;
    }
  }
  sh[t] = run;
  __syncthreads();
  if (t == 0){
    int acc = 0;
    for (int i = 0; i < np; ++i){ int v = sh[i]; sh[i] = acc; acc += v; }
    PST[y*PSTW + np] = nE;
    RP[rel_rpoff(y) + rel_n(y)] = nE;
  }
  __syncthreads();
  if (t < np){
    int base = sh[t];
    PST[y*PSTW + t] = base;
    for (int c = 0; c < ECH; ++c){
      size_t idx = (((size_t)y*ECH + c)<<6) + t;
      PC[idx] += base;
    }
  }
}

__global__ __launch_bounds__(256) void csrC_kernel(
    const int* __restrict__ s0p, const int* __restrict__ d0p,
    const int* __restrict__ s1p, const int* __restrict__ d1p,
    const int* __restrict__ s2p, const int* __restrict__ d2p,
    const int* __restrict__ s3p, const int* __restrict__ d3p,
    const int* __restrict__ PC, int* __restrict__ EB, int nE){
  int y = blockIdx.y;
  const int* src = y==0?s0p: y==1?s1p: y==2?s2p:s3p;
  const int* dst = y==0?d0p: y==1?d1p: y==2?d2p:d3p;
  int shift = rel_shift(y);
  int mask = (1<<shift) - 1;
  __shared__ int cur[64];
  int t = threadIdx.x;
  if (t < 64) cur[t] = PC[(((size_t)y*ECH + blockIdx.x)<<6) + t];
  __syncthreads();
  int CH = (nE + ECH - 1)/ECH;
  int e0 = blockIdx.x*CH, e1 = e0 + CH; if (e1 > nE) e1 = nE;
  int* eb = EB + (size_t)y*nE;
  for (int e = e0 + t*4; e < e1; e += 1024){
    #pragma unroll
    for (int u = 0; u < 4; ++u){
      int ee = e + u;
      if (ee < e1){
        int d = dst[ee], s = src[ee];
        int pos = atomicAdd(&cur[d>>shift], 1);
        eb[pos] = ((d & mask) << 17) | s;
      }
    }
  }
}

__global__ __launch_bounds__(256) void csrD_kernel(const int* __restrict__ EB, const int* __restrict__ PST,
    int* __restrict__ RP, float* __restrict__ INV,
    int* __restrict__ ss0, int* __restrict__ ss1, int* __restrict__ ss2, int* __restrict__ ss3, int nE){
  int y = blockIdx.y;
  int np = rel_np(y);
  int part = blockIdx.x;
  if (part >= np) return;
  int shift = rel_shift(y);
  int n = rel_n(y);
  int gbase = part << shift;
  int len = n - gbase; int range = 1 << shift; if (len > range) len = range;
  __shared__ int cnt[2048];
  __shared__ int curs[2048];
  __shared__ int sh[256];
  int t = threadIdx.x;
  for (int i = t; i < len; i += 256) cnt[i] = 0;
  __syncthreads();
  const int* eb = EB + (size_t)y*nE;
  int j0 = PST[y*PSTW + part], j1 = PST[y*PSTW + part + 1];
  for (int j = j0 + t*4; j < j1; j += 1024){
    int a = eb[j];
    int b = (j+1 < j1) ? eb[j+1] : -1;
    int c = (j+2 < j1) ? eb[j+2] : -1;
    int d = (j+3 < j1) ? eb[j+3] : -1;
    atomicAdd(&cnt[a>>17], 1);
    if (b >= 0) atomicAdd(&cnt[b>>17], 1);
    if (c >= 0) atomicAdd(&cnt[c>>17], 1);
    if (d >= 0) atomicAdd(&cnt[d>>17], 1);
  }
  __syncthreads();
  int base8 = t*8;
  int vals[8]; int tsum = 0;
  #pragma unroll
  for (int u = 0; u < 8; ++u){
    int i = base8 + u;
    int v = (i < len) ? cnt[i] : 0;
    vals[u] = tsum; tsum += v;
  }
  sh[t] = tsum;
  __syncthreads();
  for (int o = 1; o < 256; o <<= 1){
    int v = (t >= o) ? sh[t-o] : 0;
    __syncthreads();
    sh[t] += v;
    __syncthreads();
  }
  int tbase = j0 + sh[t] - tsum;
  int rpo = rel_rpoff(y) + gbase;
  int ivo = rel_coff(y) + gbase;
  #pragma unroll
  for (int u = 0; u < 8; ++u){
    int i = base8 + u;
    if (i < len){
      int start = tbase + vals[u];
      curs[i] = start;
      RP[rpo + i] = start;
      INV[ivo + i] = 1.f/fmaxf((float)cnt[i], 1.f);
    }
  }
  __syncthreads();
  int* ss = y==0?ss0: y==1?ss1: y==2?ss2:ss3;
  for (int j = j0 + t*4; j < j1; j += 1024){
    #pragma unroll
    for (int u = 0; u < 4; ++u){
      int jj = j + u;
      if (jj < j1){
        int pk = eb[jj];
        int pos = atomicAdd(&curs[pk>>17], 1);
        ss[pos] = pk & 0x1FFFF;
      }
    }
  }
}

// ---------------- fused weight prep (grid.y = 0..15) ----------------
__global__ __launch_bounds__(256) void wprep_kernel(const float* __restrict__ Wl, const float* __restrict__ Wr,
    const float* __restrict__ Wp, const float* __restrict__ Wc1, const float* __restrict__ Wv1,
    const float* __restrict__ bc1, const float* __restrict__ bv1,
    u16* __restrict__ WTl, u16* __restrict__ WTr1, u16* __restrict__ WTr3, u16* __restrict__ WT02,
    u16* __restrict__ WTH, u16* __restrict__ WTp, float* __restrict__ bH){
  int y = blockIdx.y;
  int i = blockIdx.x*256 + threadIdx.x;
  if (y < 8){
    if (i < 65536){ int k=i>>8, n=i&255; WTl[(size_t)y*65536 + n*256 + k] = f2bf(Wl[(size_t)y*65536 + i]); }
  } else if (y < 10){
    int l = y-8;
    if (i < 65536){ int k=i>>8, n=i&255; WTr1[(size_t)l*65536 + n*256 + k] = f2bf(Wr[(size_t)(l*4+1)*65536 + i]); }
  } else if (y < 12){
    int l = y-10;
    if (i < 65536){ int k=i>>8, n=i&255; WTr3[(size_t)l*65536 + n*256 + k] = f2bf(Wr[(size_t)(l*4+3)*65536 + i]); }
  } else if (y < 14){
    int l = y-12;
    if (i < 65536){ int k=i>>8, n=i&255;
      WT02[(size_t)l*65536 + n*256 + k] = f2bf(Wr[(size_t)(l*4+0)*65536 + i] + Wr[(size_t)(l*4+2)*65536 + i]); }
  } else if (y == 14){
    if (i < 65536){ int k=i>>8, n=i&255;
      float v = (n < 128) ? Wc1[k*128 + n] : Wv1[k*128 + (n-128)];
      WTH[(size_t)n*256 + k] = f2bf(v); }
  } else {
    if (i < 8192){ int k=i>>8, n=i&255; WTp[(size_t)n*32 + k] = f2bf(Wp[i]); }
    if (i < 256) bH[i] = (i < 128) ? bc1[i] : bv1[i-128];
  }
}

// fused f32->bf16 conversions (y=0: x_user, y=1: x_merch)
__global__ __launch_bounds__(256) void cvt2_kernel(const float* __restrict__ xu,
    const float* __restrict__ xm, u16* __restrict__ XU, u16* __restrict__ XM){
  int y = blockIdx.y;
  const float* in = y==0?xu:xm;
  u16* out = y==0?XU:XM;
  int n4 = y==0?NUSER*HD/4:NMERCH*HD/4;
  int i = blockIdx.x*256 + threadIdx.x;
  if (i >= n4) return;
  float4 v = ((const float4*)in)[i];
  ushort4 o; o.x = f2bf(v.x); o.y = f2bf(v.y); o.z = f2bf(v.z); o.w = f2bf(v.w);
  ((ushort4*)out)[i] = o;
}

// ---------------- proj GEMM: XT = bf16(x_tx[f32, Mx32] @ WTp[256x32] + bp) ----------------
__global__ __launch_bounds__(256) void proj_gemm_kernel(const float* __restrict__ A, const u16* __restrict__ WT,
    const float* __restrict__ bias, u16* __restrict__ C, int M){
  __shared__ u16 As[128][40];
  __shared__ u16 Bs[128][40];
  int m0 = blockIdx.x * 128, n0 = blockIdx.y * 128;
  int t = threadIdx.x;
  int w = t >> 6, lane = t & 63;
  int wm = (w >> 1) << 6, wn = (w & 1) << 6;
  int lm = lane & 15;
  int lk = (lane >> 4) << 3;
  int sr = t >> 1, sc = (t & 1) << 4;
  float4 f0 = {0,0,0,0}, f1 = {0,0,0,0}, f2 = {0,0,0,0}, f3 = {0,0,0,0};
  if (m0 + sr < M){
    const float* ap = A + (size_t)(m0+sr)*32 + sc;
    f0 = *(const float4*)(ap+0); f1 = *(const float4*)(ap+4);
    f2 = *(const float4*)(ap+8); f3 = *(const float4*)(ap+12);
  }
  uint4 q0, q1;
  q0.x = pk2(f0.x,f0.y); q0.y = pk2(f0.z,f0.w); q0.z = pk2(f1.x,f1.y); q0.w = pk2(f1.z,f1.w);
  q1.x = pk2(f2.x,f2.y); q1.y = pk2(f2.z,f2.w); q1.z = pk2(f3.x,f3.y); q1.w = pk2(f3.z,f3.w);
  *(uint4*)&As[sr][sc] = q0;
  *(uint4*)&As[sr][sc+8] = q1;
  const u16* bp_ = WT + (size_t)(n0+sr)*32 + sc;
  *(uint4*)&Bs[sr][sc]   = *(const uint4*)(bp_);
  *(uint4*)&Bs[sr][sc+8] = *(const uint4*)(bp_ + 8);
  __syncthreads();
  bf16x8 af[4], bf[4];
  #pragma unroll
  for (int i = 0; i < 4; ++i) af[i] = *(const bf16x8*)&As[wm + i*16 + lm][lk];
  #pragma unroll
  for (int j = 0; j < 4; ++j) bf[j] = *(const bf16x8*)&Bs[wn + j*16 + lm][lk];
  f32x4 acc[4][4] = {};
  #pragma unroll
  for (int i = 0; i < 4; ++i)
    #pragma unroll
    for (int j = 0; j < 4; ++j)
      acc[i][j] = __builtin_amdgcn_mfma_f32_16x16x32_bf16(af[i], bf[j], acc[i][j], 0, 0, 0);
  int rsub = (lane >> 4) << 2;
  #pragma unroll
  for (int j = 0; j < 4; ++j){
    int col = n0 + wn + j*16 + lm;
    float bv = bias[col];
    #pragma unroll
    for (int i = 0; i < 4; ++i){
      int rbase = m0 + wm + i*16 + rsub;
      #pragma unroll
      for (int r = 0; r < 4; ++r){
        int row = rbase + r;
        if (row < M) C[(size_t)row*HD + col] = f2bf(acc[i][j][r] + bv);
      }
    }
  }
}

// ---------------- device bodies for mega kernels ----------------
// C = bf16(A[Mx256] @ WT[256x256]^T-layout), no bias/relu. As/Bs: u16[128*40] each.
__device__ __forceinline__ void gemm_nb_body(const u16* __restrict__ A, const u16* __restrict__ WT,
    u16* __restrict__ C, int M, int m0, int n0, u16* As, u16* Bs){
  int t = threadIdx.x;
  int w = t >> 6, lane = t & 63;
  int wm = (w >> 1) << 6, wn = (w & 1) << 6;
  int lm = lane & 15;
  int lk = (lane >> 4) << 3;
  f32x4 acc[4][4] = {};
  int sr0 = t >> 2, sk0 = (t & 3) << 3;
  int sr1 = sr0 + 64;
  for (int k0 = 0; k0 < 256; k0 += 32){
    uint4 a0 = *(const uint4*)(A  + (size_t)(m0+sr0)*256 + k0 + sk0);
    uint4 a1 = *(const uint4*)(A  + (size_t)(m0+sr1)*256 + k0 + sk0);
    uint4 b0 = *(const uint4*)(WT + (size_t)(n0+sr0)*256 + k0 + sk0);
    uint4 b1 = *(const uint4*)(WT + (size_t)(n0+sr1)*256 + k0 + sk0);
    *(uint4*)&As[sr0*40 + sk0] = a0;
    *(uint4*)&As[sr1*40 + sk0] = a1;
    *(uint4*)&Bs[sr0*40 + sk0] = b0;
    *(uint4*)&Bs[sr1*40 + sk0] = b1;
    __syncthreads();
    bf16x8 af[4], bf[4];
    #pragma unroll
    for (int i = 0; i < 4; ++i) af[i] = *(const bf16x8*)&As[(wm + i*16 + lm)*40 + lk];
    #pragma unroll
    for (int j = 0; j < 4; ++j) bf[j] = *(const bf16x8*)&Bs[(wn + j*16 + lm)*40 + lk];
    #pragma unroll
    for (int i = 0; i < 4; ++i)
      #pragma unroll
      for (int j = 0; j < 4; ++j)
        acc[i][j] = __builtin_amdgcn_mfma_f32_16x16x32_bf16(af[i], bf[j], acc[i][j], 0, 0, 0);
    __syncthreads();
  }
  int rsub = (lane >> 4) << 2;
  #pragma unroll
  for (int j = 0; j < 4; ++j){
    int col = n0 + wn + j*16 + lm;
    #pragma unroll
    for (int i = 0; i < 4; ++i){
      int rbase = m0 + wm + i*16 + rsub;
      #pragma unroll
      for (int r = 0; r < 4; ++r){
        int row = rbase + r;
        if (row < M) C[(size_t)row*256 + col] = f2bf(acc[i][j][r]);
      }
    }
  }
}

// C = bf16(relu(G@Wa + X@Wb + bias)), virtual K=512
__device__ __forceinline__ void gemm2_body(const u16* __restrict__ G, const u16* __restrict__ X,
    const u16* __restrict__ Wa, const u16* __restrict__ Wb, const float* __restrict__ bias,
    u16* __restrict__ C, int M, int m0, int n0, u16* As, u16* Bs){
  int t = threadIdx.x;
  int w = t >> 6, lane = t & 63;
  int wm = (w >> 1) << 6, wn = (w & 1) << 6;
  int lm = lane & 15;
  int lk = (lane >> 4) << 3;
  f32x4 acc[4][4] = {};
  int sr0 = t >> 2, sk0 = (t & 3) << 3;
  int sr1 = sr0 + 64;
  for (int k0 = 0; k0 < 512; k0 += 32){
    const u16* A  = (k0 < 256) ? G : X;
    const u16* WT = (k0 < 256) ? Wa : Wb;
    int kk = k0 & 255;
    uint4 a0 = *(const uint4*)(A  + (size_t)(m0+sr0)*256 + kk + sk0);
    uint4 a1 = *(const uint4*)(A  + (size_t)(m0+sr1)*256 + kk + sk0);
    uint4 b0_ = *(const uint4*)(WT + (size_t)(n0+sr0)*256 + kk + sk0);
    uint4 b1_ = *(const uint4*)(WT + (size_t)(n0+sr1)*256 + kk + sk0);
    *(uint4*)&As[sr0*40 + sk0] = a0;
    *(uint4*)&As[sr1*40 + sk0] = a1;
    *(uint4*)&Bs[sr0*40 + sk0] = b0_;
    *(uint4*)&Bs[sr1*40 + sk0] = b1_;
    __syncthreads();
    bf16x8 af[4], bf[4];
    #pragma unroll
    for (int i = 0; i < 4; ++i) af[i] = *(const bf16x8*)&As[(wm + i*16 + lm)*40 + lk];
    #pragma unroll
    for (int j = 0; j < 4; ++j) bf[j] = *(const bf16x8*)&Bs[(wn + j*16 + lm)*40 + lk];
    #pragma unroll
    for (int i = 0; i < 4; ++i)
      #pragma unroll
      for (int j = 0; j < 4; ++j)
        acc[i][j] = __builtin_amdgcn_mfma_f32_16x16x32_bf16(af[i], bf[j], acc[i][j], 0, 0, 0);
    __syncthreads();
  }
  int rsub = (lane >> 4) << 2;
  #pragma unroll
  for (int j = 0; j < 4; ++j){
    int col = n0 + wn + j*16 + lm;
    float bv = bias[col];
    #pragma unroll
    for (int i = 0; i < 4; ++i){
      int rbase = m0 + wm + i*16 + rsub;
      #pragma unroll
      for (int r = 0; r < 4; ++r){
        int row = rbase + r;
        if (row < M) C[(size_t)row*256 + col] = f2bf(fmaxf(acc[i][j][r] + bv, 0.f));
      }
    }
  }
}

__device__ __forceinline__ void gather_body(const u16* __restrict__ XT,
    const int* __restrict__ rp, const int* __restrict__ ss, const float* __restrict__ inv,
    u16* __restrict__ out, int M, int bx){
  int d = bx*4 + (threadIdx.x >> 6);
  if (d >= M) return;
  int lane = threadIdx.x & 63;
  int c = lane << 2;
  float o0=0,o1=0,o2=0,o3=0;
  gather4(XT, ss, rp[d], rp[d+1], lane, c, o0, o1, o2, o3);
  float sc = inv[d];
  ushort4 o; o.x = f2bf(o0*sc); o.y = f2bf(o1*sc); o.z = f2bf(o2*sc); o.w = f2bf(o3*sc);
  *(ushort4*)(out + (size_t)d*HD + c) = o;
}

__device__ __forceinline__ void fused_tx_body(const u16* __restrict__ ACCb,
    const u16* __restrict__ Tu, const u16* __restrict__ Tm,
    const int* __restrict__ rpu, const int* __restrict__ ssu, const float* __restrict__ invu,
    const int* __restrict__ rpm, const int* __restrict__ ssm, const float* __restrict__ invm,
    const float* __restrict__ b0, const float* __restrict__ b2, u16* __restrict__ XT, int M, int bx){
  int d = bx*4 + (threadIdx.x >> 6);
  if (d >= M) return;
  int lane = threadIdx.x & 63;
  int c = lane << 2;
  ushort4 av = *(const ushort4*)(ACCb + (size_t)d*HD + c);
  float r0 = bf2f(av.x), r1 = bf2f(av.y), r2 = bf2f(av.z), r3 = bf2f(av.w);
  {
    float s0=0,s1=0,s2=0,s3=0;
    gather4(Tu, ssu, rpu[d], rpu[d+1], lane, c, s0, s1, s2, s3);
    float sc = invu[d];
    r0 += s0*sc; r1 += s1*sc; r2 += s2*sc; r3 += s3*sc;
  }
  {
    float s0=0,s1=0,s2=0,s3=0;
    gather4(Tm, ssm, rpm[d], rpm[d+1], lane, c, s0, s1, s2, s3);
    float sc = invm[d];
    r0 += s0*sc; r1 += s1*sc; r2 += s2*sc; r3 += s3*sc;
  }
  float4 bb0 = *(const float4*)(b0 + c);
  float4 bb2 = *(const float4*)(b2 + c);
  ushort4 o;
  o.x = f2bf(fmaxf(0.5f*(r0 + bb0.x + bb2.x), 0.f));
  o.y = f2bf(fmaxf(0.5f*(r1 + bb0.y + bb2.y), 0.f));
  o.z = f2bf(fmaxf(0.5f*(r2 + bb0.z + bb2.z), 0.f));
  o.w = f2bf(fmaxf(0.5f*(r3 + bb0.w + bb2.w), 0.f));
  *(ushort4*)(XT + (size_t)d*HD + c) = o;
}

// ---------------- megaA: root GEMM + transform GEMMs + tm/tu gathers (independent group) ----------------
// blocks: [0,1564) root | [1564,1958) pair transforms | [1958,3208) tm gather | [3208,8208) tu gather
__global__ __launch_bounds__(256) void megaA_kernel(
    const u16* __restrict__ XT, const u16* __restrict__ WT02l, u16* __restrict__ ACCb,
    const u16* __restrict__ xu, const u16* __restrict__ Wl0, u16* __restrict__ Tu,
    const u16* __restrict__ xm, const u16* __restrict__ Wl2, u16* __restrict__ Tm,
    const int* __restrict__ rp_tm, const int* __restrict__ ss_tm, const float* __restrict__ inv_tm, u16* __restrict__ AGGM,
    const int* __restrict__ rp_tu, const int* __restrict__ ss_tu, const float* __restrict__ inv_tu, u16* __restrict__ AGGU){
  __shared__ u16 smem[10240];
  int b = blockIdx.x;
  if (b < 1564){
    int ny = (b >= 782) ? 1 : 0;
    int x = b - ny*782;
    gemm_nb_body(XT, WT02l, ACCb, NTX, x*128, ny*128, smem, smem + 5120);
  } else if (b < 1958){
    int bb = b - 1564;
    if (bb < 314){
      int ny = bb / 157, x = bb - ny*157;
      gemm_nb_body(xu, Wl0, Tu, NUSER, x*128, ny*128, smem, smem + 5120);
    } else {
      bb -= 314;
      int ny = bb / 40, x = bb - ny*40;
      gemm_nb_body(xm, Wl2, Tm, NMERCH, x*128, ny*128, smem, smem + 5120);
    }
  } else if (b < 3208){
    gather_body(XT, rp_tm, ss_tm, inv_tm, AGGM, NMERCH, b - 1958);
  } else {
    gather_body(XT, rp_tu, ss_tu, inv_tu, AGGU, NUSER, b - 3208);
  }
}

// ---------------- megaB: update GEMMs + fused_tx (independent group) ----------------
// blocks: [0,314) user upd | [314,394) merch upd | [394,25394) fused_tx
__global__ __launch_bounds__(256) void megaB_kernel(
    const u16* __restrict__ AGGU, const u16* __restrict__ xu, const u16* __restrict__ Wa3,
    const u16* __restrict__ Wb3, const float* __restrict__ b3, u16* __restrict__ xu_nxt,
    const u16* __restrict__ AGGM, const u16* __restrict__ xm, const u16* __restrict__ Wa1,
    const u16* __restrict__ Wb1, const float* __restrict__ b1, u16* __restrict__ xm_nxt,
    const u16* __restrict__ ACCb, const u16* __restrict__ Tu, const u16* __restrict__ Tm,
    const int* __restrict__ rpu, const int* __restrict__ ssu, const float* __restrict__ invu,
    const int* __restrict__ rpm, const int* __restrict__ ssm, const float* __restrict__ invm,
    const float* __restrict__ bb0, const float* __restrict__ bb2, u16* __restrict__ XT){
  __shared__ u16 smem[10240];
  int b = blockIdx.x;
  if (b < 314){
    int ny = b / 157, x = b - ny*157;
    gemm2_body(AGGU, xu, Wa3, Wb3, b3, xu_nxt, NUSER, x*128, ny*128, smem, smem + 5120);
  } else if (b < 394){
    int bb = b - 314;
    int ny = bb / 40, x = bb - ny*40;
    gemm2_body(AGGM, xm, Wa1, Wb1, b1, xm_nxt, NMERCH, x*128, ny*128, smem, smem + 5120);
  } else {
    fused_tx_body(ACCb, Tu, Tm, rpu, ssu, invu, rpm, ssm, invm, bb0, bb2, XT, NTX, b - 394);
  }
}

// ---------------- fused head: out = (relu(XT@[Wc1|Wv1]+bH)) @ {Wc2|Wv2} + {bc2|bv2} ----------------
__global__ __launch_bounds__(256) void fused_head_kernel(const u16* __restrict__ A, const u16* __restrict__ BT,
    const float* __restrict__ bias, const float* __restrict__ Wc2, const float* __restrict__ bc2,
    const float* __restrict__ Wv2, const float* __restrict__ bv2, float* __restrict__ out, int M){
  __shared__ u16 As[128][40];
  __shared__ u16 Bs[128][40];
  __shared__ float hpart[128];
  int m0 = blockIdx.x * 128, n0 = blockIdx.y * 128;
  int t = threadIdx.x;
  int w = t >> 6, lane = t & 63;
  int wm = (w >> 1) << 6, wn = (w & 1) << 6;
  int lm = lane & 15;
  int lk = (lane >> 4) << 3;
  if (t < 128) hpart[t] = 0.f;
  f32x4 acc[4][4] = {};
  int sr0 = t >> 2, sk0 = (t & 3) << 3;
  int sr1 = sr0 + 64;
  for (int k0 = 0; k0 < 256; k0 += 32){
    uint4 a0 = *(const uint4*)(A  + (size_t)(m0+sr0)*256 + k0 + sk0);
    uint4 a1 = *(const uint4*)(A  + (size_t)(m0+sr1)*256 + k0 + sk0);
    uint4 b0 = *(const uint4*)(BT + (size_t)(n0+sr0)*256 + k0 + sk0);
    uint4 b1 = *(const uint4*)(BT + (size_t)(n0+sr1)*256 + k0 + sk0);
    *(uint4*)&As[sr0][sk0] = a0;
    *(uint4*)&As[sr1][sk0] = a1;
    *(uint4*)&Bs[sr0][sk0] = b0;
    *(uint4*)&Bs[sr1][sk0] = b1;
    __syncthreads();
    bf16x8 af[4], bf[4];
    #pragma unroll
    for (int i = 0; i < 4; ++i) af[i] = *(const bf16x8*)&As[wm + i*16 + lm][lk];
    #pragma unroll
    for (int j = 0; j < 4; ++j) bf[j] = *(const bf16x8*)&Bs[wn + j*16 + lm][lk];
    #pragma unroll
    for (int i = 0; i < 4; ++i)
      #pragma unroll
      for (int j = 0; j < 4; ++j)
        acc[i][j] = __builtin_amdgcn_mfma_f32_16x16x32_bf16(af[i], bf[j], acc[i][j], 0, 0, 0);
    __syncthreads();
  }
  const float* w2 = blockIdx.y ? Wv2 : Wc2;
  float badd = blockIdx.y ? bv2[0] : bc2[0];
  size_t outoff = blockIdx.y ? (size_t)M : 0;
  int rsub = (lane >> 4) << 2;
  float w2v[4], bv[4];
  #pragma unroll
  for (int j = 0; j < 4; ++j){
    w2v[j] = w2[wn + j*16 + lm];
    bv[j]  = bias[n0 + wn + j*16 + lm];
  }
  #pragma unroll
  for (int i = 0; i < 4; ++i){
    #pragma unroll
    for (int r = 0; r < 4; ++r){
      float p = 0.f;
      #pragma unroll
      for (int j = 0; j < 4; ++j) p += fmaxf(acc[i][j][r] + bv[j], 0.f) * w2v[j];
      p += __shfl_xor(p, 1); p += __shfl_xor(p, 2);
      p += __shfl_xor(p, 4); p += __shfl_xor(p, 8);
      if (lm == 0) atomicAdd(&hpart[wm + i*16 + rsub + r], p);
    }
  }
  __syncthreads();
  if (t < 128){
    int row = m0 + t;
    if (row < M) out[outoff + row] = hpart[t] + badd;
  }
}

extern "C" void kernel_launch(void* const* d_in, const int* in_sizes, int n_in,
                              void* d_out, int out_size, void* d_ws, size_t ws_size,
                              hipStream_t stream){
  const float* x_tx   = (const float*)d_in[0];
  const float* x_user = (const float*)d_in[1];
  const float* x_merch= (const float*)d_in[2];
  const float* Wp  = (const float*)d_in[3];
  const float* bp  = (const float*)d_in[4];
  const float* Wl  = (const float*)d_in[5];
  const float* bl  = (const float*)d_in[6];
  const float* Wr  = (const float*)d_in[7];
  const float* Wc1 = (const float*)d_in[8];
  const float* bc1 = (const float*)d_in[9];
  const float* Wc2 = (const float*)d_in[10];
  const float* bc2 = (const float*)d_in[11];
  const float* Wv1 = (const float*)d_in[12];
  const float* bv1 = (const float*)d_in[13];
  const float* Wv2 = (const float*)d_in[14];
  const float* bv2 = (const float*)d_in[15];
  const int* e_ut_s = (const int*)d_in[16];
  const int* e_ut_d = (const int*)d_in[17];
  const int* e_tm_s = (const int*)d_in[18];
  const int* e_tm_d = (const int*)d_in[19];
  const int* e_mt_s = (const int*)d_in[20];
  const int* e_mt_d = (const int*)d_in[21];
  const int* e_tu_s = (const int*)d_in[22];
  const int* e_tu_d = (const int*)d_in[23];
  float* out = (float*)d_out;
  const int NE = in_sizes[16];

  // ---- workspace layout (~176 MB) ----
  char* p = (char*)d_ws;
  auto take = [&](size_t bytes)->char*{ char* r = p; p += (bytes + 255) & ~(size_t)255; return r; };
  u16*   XT    = (u16*)  take((size_t)(NTX+ROWPAD)*HD*2);
  u16*   ACCb  = (u16*)  take((size_t)(NTX+ROWPAD)*HD*2);
  u16*   Tu    = (u16*)  take((size_t)NUSER*HD*2);
  u16*   Tm    = (u16*)  take((size_t)NMERCH*HD*2);
  u16*   AGGU  = (u16*)  take((size_t)(NUSER+ROWPAD)*HD*2);
  u16*   AGGM  = (u16*)  take((size_t)(NMERCH+ROWPAD)*HD*2);
  u16*   XU0   = (u16*)  take((size_t)(NUSER+ROWPAD)*HD*2);
  u16*   XU1   = (u16*)  take((size_t)(NUSER+ROWPAD)*HD*2);
  u16*   XM0   = (u16*)  take((size_t)(NMERCH+ROWPAD)*HD*2);
  u16*   XM1   = (u16*)  take((size_t)(NMERCH+ROWPAD)*HD*2);
  float* INV   = (float*)take((size_t)225000*4);
  int*   RP    = (int*)  take((size_t)225008*4);
  int*   SS_ut = (int*)  take((size_t)NE*4);
  int*   SS_tm = (int*)  take((size_t)NE*4);
  int*   SS_mt = (int*)  take((size_t)NE*4);
  int*   SS_tu = (int*)  take((size_t)NE*4);
  int*   PC    = (int*)  take((size_t)4*ECH*64*4);
  int*   PST   = (int*)  take((size_t)4*PSTW*4);
  int*   EB    = (int*)  take((size_t)4*NE*4);
  u16*   WTp   = (u16*)  take((size_t)32*256*2);
  u16*   WTl   = (u16*)  take((size_t)8*65536*2);
  u16*   WTr1  = (u16*)  take((size_t)2*65536*2);
  u16*   WTr3  = (u16*)  take((size_t)2*65536*2);
  u16*   WT02  = (u16*)  take((size_t)2*65536*2);
  u16*   WTH   = (u16*)  take((size_t)65536*2);
  float* bH    = (float*)take((size_t)256*4);

  float* inv_ut = INV,  *inv_tm = INV+100000, *inv_mt = INV+105000, *inv_tu = INV+205000;
  int*   rp_ut  = RP,   *rp_tm  = RP+100001,  *rp_mt  = RP+105002,  *rp_tu  = RP+205003;

  // ---- CSR build: radix partition ----
  csrA_kernel<<<dim3(ECH,4),256,0,stream>>>(e_ut_d, e_tm_d, e_mt_d, e_tu_d, NE, PC);
  csrB_kernel<<<dim3(1,4),64,0,stream>>>(PC, PST, RP, NE);
  csrC_kernel<<<dim3(ECH,4),256,0,stream>>>(e_ut_s, e_ut_d, e_tm_s, e_tm_d, e_mt_s, e_mt_d,
      e_tu_s, e_tu_d, PC, EB, NE);
  csrD_kernel<<<dim3(49,4),256,0,stream>>>(EB, PST, RP, INV, SS_ut, SS_tm, SS_mt, SS_tu, NE);

  // ---- weight prep ----
  wprep_kernel<<<dim3(256,16),256,0,stream>>>(Wl, Wr, Wp, Wc1, Wv1, bc1, bv1,
      WTl, WTr1, WTr3, WT02, WTH, WTp, bH);

  // ---- init activations ----
  cvt2_kernel<<<dim3(5000,2),256,0,stream>>>(x_user, x_merch, XU0, XM0);
  proj_gemm_kernel<<<dim3(782,2),256,0,stream>>>(x_tx, WTp, bp, XT, NTX);

  u16* xu_cur = XU0; u16* xu_nxt = XU1;
  u16* xm_cur = XM0; u16* xm_nxt = XM1;

  for (int l = 0; l < 2; ++l){
    const float* bl_l = bl + (size_t)l*4*256;
    u16* WTl_l = WTl + (size_t)l*4*65536;

    // group A (all independent): root GEMM -> ACCb, Tu/Tm transforms, tm/tu gathers
    megaA_kernel<<<8208,256,0,stream>>>(
        XT, WT02 + (size_t)l*65536, ACCb,
        xu_cur, WTl_l + 0*65536, Tu,
        xm_cur, WTl_l + 2*65536, Tm,
        rp_tm, SS_tm, inv_tm, AGGM,
        rp_tu, SS_tu, inv_tu, AGGU);

    // group B (all independent): user/merch updates + fused tx epilogue -> XT (in place)
    megaB_kernel<<<25394,256,0,stream>>>(
        AGGU, xu_cur, WTl_l + 3*65536, WTr3 + (size_t)l*65536, bl_l + 3*256, xu_nxt,
        AGGM, xm_cur, WTl_l + 1*65536, WTr1 + (size_t)l*65536, bl_l + 1*256, xm_nxt,
        ACCb, Tu, Tm,
        rp_ut, SS_ut, inv_ut, rp_mt, SS_mt, inv_mt,
        bl_l + 0*256, bl_l + 2*256, XT);

    { u16* tmp = xu_cur; xu_cur = xu_nxt; xu_nxt = tmp; }
    { u16* tmp = xm_cur; xm_cur = xm_nxt; xm_nxt = tmp; }
  }

  // fused heads (direct out write)
  fused_head_kernel<<<dim3(782,2),256,0,stream>>>(XT, WTH, bH, Wc2, bc2, Wv2, bv2, out, NTX);
}

// Round 17
// 542.207 us; speedup vs baseline: 1.1915x; 1.1915x over previous
//
#include <hip/hip_runtime.h>

#define NTX 100000
#define NUSER 20000
#define NMERCH 5000
#define HD 256
#define ROWPAD 128

using u16 = unsigned short;
typedef __attribute__((ext_vector_type(8))) short bf16x8;
typedef __attribute__((ext_vector_type(4))) float f32x4;

__device__ __forceinline__ u16 f2bf(float f){
  unsigned u = __float_as_uint(f);
  unsigned r = (u + 0x7FFFu + ((u >> 16) & 1u)) >> 16;
  return (u16)r;
}
__device__ __forceinline__ float bf2f(u16 b){
  return __uint_as_float(((unsigned)b) << 16);
}
__device__ __forceinline__ unsigned pk2(float a, float b){
  return (unsigned)f2bf(a) | ((unsigned)f2bf(b) << 16);
}

// full-row gather (8B/lane, 64 lanes per row): cooperative index load + shfl + 4 chains.
// 28 VGPR / ~70% occupancy — measured best point.
__device__ __forceinline__ void gather4(const u16* __restrict__ T, const int* __restrict__ ss,
    int j0, int j1, int lane, int c, float& o0, float& o1, float& o2, float& o3){
  float a0=0,a1=0,a2=0,a3=0, b0=0,b1=0,b2=0,b3=0;
  float c0=0,c1=0,c2=0,c3=0, d0=0,d1=0,d2=0,d3=0;
  for (int base = j0; base < j1; base += 64){
    int n = j1 - base; if (n > 64) n = 64;
    int idx = ss[base + (lane < n ? lane : 0)];
    for (int jj = 0; jj < n; jj += 4){
      int s0 = __shfl(idx, jj);
      int s1 = __shfl(idx, jj+1);
      int s2 = __shfl(idx, jj+2);
      int s3 = __shfl(idx, jj+3);
      ushort4 v0 = *(const ushort4*)(T + (size_t)s0*HD + c);
      ushort4 v1 = *(const ushort4*)(T + (size_t)s1*HD + c);
      ushort4 v2 = *(const ushort4*)(T + (size_t)s2*HD + c);
      ushort4 v3 = *(const ushort4*)(T + (size_t)s3*HD + c);
      a0 += bf2f(v0.x); a1 += bf2f(v0.y); a2 += bf2f(v0.z); a3 += bf2f(v0.w);
      if (jj+1 < n){ b0 += bf2f(v1.x); b1 += bf2f(v1.y); b2 += bf2f(v1.z); b3 += bf2f(v1.w); }
      if (jj+2 < n){ c0 += bf2f(v2.x); c1 += bf2f(v2.y); c2 += bf2f(v2.z); c3 += bf2f(v2.w); }
      if (jj+3 < n){ d0 += bf2f(v3.x); d1 += bf2f(v3.y); d2 += bf2f(v3.z); d3 += bf2f(v3.w); }
    }
  }
  o0 += (a0+b0)+(c0+d0); o1 += (a1+b1)+(c1+d1);
  o2 += (a2+b2)+(c2+d2); o3 += (a3+b3)+(c3+d3);
}

// ---------------- CSR radix-partition build (blockIdx.y = relation: 0=ut,1=tm,2=mt,3=tu) ----------------
__device__ __forceinline__ int rel_n(int y){ return y==0?NTX: y==1?NMERCH: y==2?NTX:NUSER; }
__device__ __forceinline__ int rel_coff(int y){ return y==0?0: y==1?100000: y==2?105000:205000; }
__device__ __forceinline__ int rel_rpoff(int y){ return y==0?0: y==1?100001: y==2?105002:205003; }
__device__ __forceinline__ int rel_shift(int y){ return y==0?11: y==1?8: y==2?11:10; }
__device__ __forceinline__ int rel_np(int y){ return y==0?49: y==1?20: y==2?49:20; }
#define ECH 128
#define PSTW 72

__global__ __launch_bounds__(256) void csrA_kernel(const int* __restrict__ d0p, const int* __restrict__ d1p,
    const int* __restrict__ d2p, const int* __restrict__ d3p, int nE, int* __restrict__ PC){
  int y = blockIdx.y;
  const int* dst = y==0?d0p: y==1?d1p: y==2?d2p:d3p;
  int shift = rel_shift(y);
  __shared__ int cc[64];
  int t = threadIdx.x;
  if (t < 64) cc[t] = 0;
  __syncthreads();
  int CH = (nE + ECH - 1)/ECH;
  int e0 = blockIdx.x*CH, e1 = e0 + CH; if (e1 > nE) e1 = nE;
  for (int e = e0 + t*4; e < e1; e += 1024){
    int a = dst[e];
    int b = (e+1 < e1) ? dst[e+1] : -1;
    int c = (e+2 < e1) ? dst[e+2] : -1;
    int d = (e+3 < e1) ? dst[e+3] : -1;
    atomicAdd(&cc[a>>shift], 1);
    if (b >= 0) atomicAdd(&cc[b>>shift], 1);
    if (c >= 0) atomicAdd(&cc[c>>shift], 1);
    if (d >= 0) atomicAdd(&cc[d>>shift], 1);
  }
  __syncthreads();
  if (t < 64) PC[(((size_t)y*ECH + blockIdx.x)<<6) + t] = cc[t];
}

__global__ void csrB_kernel(int* __restrict__ PC, int* __restrict__ PST, int* __restrict__ RP, int nE){
  int y = blockIdx.y;
  int np = rel_np(y);
  int t = threadIdx.x;
  __shared__ int sh[64];
  int run = 0;
  if (t < np){
    for (int c = 0; c < ECH; ++c){
      size_t idx = (((size_t)y*ECH + c)<<6) + t;
      int v = PC[idx]; PC[idx] = run; run += v;
    }
  }
  sh[t] = run;
  __syncthreads();
  if (t == 0){
    int acc = 0;
    for (int i = 0; i < np; ++i){ int v = sh[i]; sh[i] = acc; acc += v; }
    PST[y*PSTW + np] = nE;
    RP[rel_rpoff(y) + rel_n(y)] = nE;
  }
  __syncthreads();
  if (t < np){
    int base = sh[t];
    PST[y*PSTW + t] = base;
    for (int c = 0; c < ECH; ++c){
      size_t idx = (((size_t)y*ECH + c)<<6) + t;
      PC[idx] += base;
    }
  }
}

__global__ __launch_bounds__(256) void csrC_kernel(
    const int* __restrict__ s0p, const int* __restrict__ d0p,
    const int* __restrict__ s1p, const int* __restrict__ d1p,
    const int* __restrict__ s2p, const int* __restrict__ d2p,
    const int* __restrict__ s3p, const int* __restrict__ d3p,
    const int* __restrict__ PC, int* __restrict__ EB, int nE){
  int y = blockIdx.y;
  const int* src = y==0?s0p: y==1?s1p: y==2?s2p:s3p;
  const int* dst = y==0?d0p: y==1?d1p: y==2?d2p:d3p;
  int shift = rel_shift(y);
  int mask = (1<<shift) - 1;
  __shared__ int cur[64];
  int t = threadIdx.x;
  if (t < 64) cur[t] = PC[(((size_t)y*ECH + blockIdx.x)<<6) + t];
  __syncthreads();
  int CH = (nE + ECH - 1)/ECH;
  int e0 = blockIdx.x*CH, e1 = e0 + CH; if (e1 > nE) e1 = nE;
  int* eb = EB + (size_t)y*nE;
  for (int e = e0 + t*4; e < e1; e += 1024){
    #pragma unroll
    for (int u = 0; u < 4; ++u){
      int ee = e + u;
      if (ee < e1){
        int d = dst[ee], s = src[ee];
        int pos = atomicAdd(&cur[d>>shift], 1);
        eb[pos] = ((d & mask) << 17) | s;
      }
    }
  }
}

__global__ __launch_bounds__(256) void csrD_kernel(const int* __restrict__ EB, const int* __restrict__ PST,
    int* __restrict__ RP, float* __restrict__ INV,
    int* __restrict__ ss0, int* __restrict__ ss1, int* __restrict__ ss2, int* __restrict__ ss3, int nE){
  int y = blockIdx.y;
  int np = rel_np(y);
  int part = blockIdx.x;
  if (part >= np) return;
  int shift = rel_shift(y);
  int n = rel_n(y);
  int gbase = part << shift;
  int len = n - gbase; int range = 1 << shift; if (len > range) len = range;
  __shared__ int cnt[2048];
  __shared__ int curs[2048];
  __shared__ int sh[256];
  int t = threadIdx.x;
  for (int i = t; i < len; i += 256) cnt[i] = 0;
  __syncthreads();
  const int* eb = EB + (size_t)y*nE;
  int j0 = PST[y*PSTW + part], j1 = PST[y*PSTW + part + 1];
  for (int j = j0 + t*4; j < j1; j += 1024){
    int a = eb[j];
    int b = (j+1 < j1) ? eb[j+1] : -1;
    int c = (j+2 < j1) ? eb[j+2] : -1;
    int d = (j+3 < j1) ? eb[j+3] : -1;
    atomicAdd(&cnt[a>>17], 1);
    if (b >= 0) atomicAdd(&cnt[b>>17], 1);
    if (c >= 0) atomicAdd(&cnt[c>>17], 1);
    if (d >= 0) atomicAdd(&cnt[d>>17], 1);
  }
  __syncthreads();
  int base8 = t*8;
  int vals[8]; int tsum = 0;
  #pragma unroll
  for (int u = 0; u < 8; ++u){
    int i = base8 + u;
    int v = (i < len) ? cnt[i] : 0;
    vals[u] = tsum; tsum += v;
  }
  sh[t] = tsum;
  __syncthreads();
  for (int o = 1; o < 256; o <<= 1){
    int v = (t >= o) ? sh[t-o] : 0;
    __syncthreads();
    sh[t] += v;
    __syncthreads();
  }
  int tbase = j0 + sh[t] - tsum;
  int rpo = rel_rpoff(y) + gbase;
  int ivo = rel_coff(y) + gbase;
  #pragma unroll
  for (int u = 0; u < 8; ++u){
    int i = base8 + u;
    if (i < len){
      int start = tbase + vals[u];
      curs[i] = start;
      RP[rpo + i] = start;
      INV[ivo + i] = 1.f/fmaxf((float)cnt[i], 1.f);
    }
  }
  __syncthreads();
  int* ss = y==0?ss0: y==1?ss1: y==2?ss2:ss3;
  for (int j = j0 + t*4; j < j1; j += 1024){
    #pragma unroll
    for (int u = 0; u < 4; ++u){
      int jj = j + u;
      if (jj < j1){
        int pk = eb[jj];
        int pos = atomicAdd(&curs[pk>>17], 1);
        ss[pos] = pk & 0x1FFFF;
      }
    }
  }
}

// ---------------- fused weight prep (grid.y = 0..15) ----------------
__global__ __launch_bounds__(256) void wprep_kernel(const float* __restrict__ Wl, const float* __restrict__ Wr,
    const float* __restrict__ Wp, const float* __restrict__ Wc1, const float* __restrict__ Wv1,
    const float* __restrict__ bc1, const float* __restrict__ bv1,
    u16* __restrict__ WTl, u16* __restrict__ WTr1, u16* __restrict__ WTr3, u16* __restrict__ WT02,
    u16* __restrict__ WTH, u16* __restrict__ WTp, float* __restrict__ bH){
  int y = blockIdx.y;
  int i = blockIdx.x*256 + threadIdx.x;
  if (y < 8){
    if (i < 65536){ int k=i>>8, n=i&255; WTl[(size_t)y*65536 + n*256 + k] = f2bf(Wl[(size_t)y*65536 + i]); }
  } else if (y < 10){
    int l = y-8;
    if (i < 65536){ int k=i>>8, n=i&255; WTr1[(size_t)l*65536 + n*256 + k] = f2bf(Wr[(size_t)(l*4+1)*65536 + i]); }
  } else if (y < 12){
    int l = y-10;
    if (i < 65536){ int k=i>>8, n=i&255; WTr3[(size_t)l*65536 + n*256 + k] = f2bf(Wr[(size_t)(l*4+3)*65536 + i]); }
  } else if (y < 14){
    int l = y-12;
    if (i < 65536){ int k=i>>8, n=i&255;
      WT02[(size_t)l*65536 + n*256 + k] = f2bf(Wr[(size_t)(l*4+0)*65536 + i] + Wr[(size_t)(l*4+2)*65536 + i]); }
  } else if (y == 14){
    if (i < 65536){ int k=i>>8, n=i&255;
      float v = (n < 128) ? Wc1[k*128 + n] : Wv1[k*128 + (n-128)];
      WTH[(size_t)n*256 + k] = f2bf(v); }
  } else {
    if (i < 8192){ int k=i>>8, n=i&255; WTp[(size_t)n*32 + k] = f2bf(Wp[i]); }
    if (i < 256) bH[i] = (i < 128) ? bc1[i] : bv1[i-128];
  }
}

// fused f32->bf16 conversions (y=0: x_user, y=1: x_merch)
__global__ __launch_bounds__(256) void cvt2_kernel(const float* __restrict__ xu,
    const float* __restrict__ xm, u16* __restrict__ XU, u16* __restrict__ XM){
  int y = blockIdx.y;
  const float* in = y==0?xu:xm;
  u16* out = y==0?XU:XM;
  int n4 = y==0?NUSER*HD/4:NMERCH*HD/4;
  int i = blockIdx.x*256 + threadIdx.x;
  if (i >= n4) return;
  float4 v = ((const float4*)in)[i];
  ushort4 o; o.x = f2bf(v.x); o.y = f2bf(v.y); o.z = f2bf(v.z); o.w = f2bf(v.w);
  ((ushort4*)out)[i] = o;
}

// ---- shared staged-store epilogue: stage bf16 rows into LDS, store coalesced uint4 ----
// smem: u16[10240] arena (>= 64*136=8704 needed). rows h*64..h*64+63 per half.
#define STAGE_STORE(EXPR_BF16)                                                     \
  {                                                                                \
    int rsub = (lane >> 4) << 2;                                                   \
    int wh = w >> 1;                                                               \
    for (int h = 0; h < 2; ++h){                                                   \
      if (wh == h){                                                                \
        _Pragma("unroll")                                                          \
        for (int j = 0; j < 4; ++j){                                               \
          int cl = wn + j*16 + lm;                                                 \
          _Pragma("unroll")                                                        \
          for (int i = 0; i < 4; ++i){                                             \
            int lr = i*16 + rsub;                                                  \
            _Pragma("unroll")                                                      \
            for (int r = 0; r < 4; ++r) smem[(lr+r)*136 + cl] = (EXPR_BF16);       \
          }                                                                        \
        }                                                                          \
      }                                                                            \
      __syncthreads();                                                             \
      int lr2 = threadIdx.x >> 2;                                                  \
      int cb = (threadIdx.x & 3) << 5;                                             \
      int grow = m0 + h*64 + lr2;                                                  \
      if (grow < M){                                                               \
        _Pragma("unroll")                                                          \
        for (int kq = 0; kq < 4; ++kq)                                             \
          *(uint4*)(C + (size_t)grow*256 + n0 + cb + kq*8) =                       \
              *(const uint4*)&smem[lr2*136 + cb + kq*8];                           \
      }                                                                            \
      __syncthreads();                                                             \
    }                                                                              \
  }

// ---------------- proj GEMM: XT = bf16(x_tx[f32, Mx32] @ WTp[256x32] + bp), staged store ----------------
__global__ __launch_bounds__(256) void proj_gemm_kernel(const float* __restrict__ A, const u16* __restrict__ WT,
    const float* __restrict__ bias, u16* __restrict__ C, int M){
  __shared__ u16 smem[10240];
  u16* As = smem; u16* Bs = smem + 5120;
  int m0 = blockIdx.x * 128, n0 = blockIdx.y * 128;
  int t = threadIdx.x;
  int w = t >> 6, lane = t & 63;
  int wm = (w >> 1) << 6, wn = (w & 1) << 6;
  int lm = lane & 15;
  int lk = (lane >> 4) << 3;
  int sr = t >> 1, sc = (t & 1) << 4;
  float4 f0 = {0,0,0,0}, f1 = {0,0,0,0}, f2 = {0,0,0,0}, f3 = {0,0,0,0};
  if (m0 + sr < M){
    const float* ap = A + (size_t)(m0+sr)*32 + sc;
    f0 = *(const float4*)(ap+0); f1 = *(const float4*)(ap+4);
    f2 = *(const float4*)(ap+8); f3 = *(const float4*)(ap+12);
  }
  uint4 q0, q1;
  q0.x = pk2(f0.x,f0.y); q0.y = pk2(f0.z,f0.w); q0.z = pk2(f1.x,f1.y); q0.w = pk2(f1.z,f1.w);
  q1.x = pk2(f2.x,f2.y); q1.y = pk2(f2.z,f2.w); q1.z = pk2(f3.x,f3.y); q1.w = pk2(f3.z,f3.w);
  *(uint4*)&As[sr*40 + sc] = q0;
  *(uint4*)&As[sr*40 + sc+8] = q1;
  const u16* bp_ = WT + (size_t)(n0+sr)*32 + sc;
  *(uint4*)&Bs[sr*40 + sc]   = *(const uint4*)(bp_);
  *(uint4*)&Bs[sr*40 + sc+8] = *(const uint4*)(bp_ + 8);
  __syncthreads();
  bf16x8 af[4], bf[4];
  #pragma unroll
  for (int i = 0; i < 4; ++i) af[i] = *(const bf16x8*)&As[(wm + i*16 + lm)*40 + lk];
  #pragma unroll
  for (int j = 0; j < 4; ++j) bf[j] = *(const bf16x8*)&Bs[(wn + j*16 + lm)*40 + lk];
  f32x4 acc[4][4] = {};
  #pragma unroll
  for (int i = 0; i < 4; ++i)
    #pragma unroll
    for (int j = 0; j < 4; ++j)
      acc[i][j] = __builtin_amdgcn_mfma_f32_16x16x32_bf16(af[i], bf[j], acc[i][j], 0, 0, 0);
  __syncthreads();
  float bcol[4];
  #pragma unroll
  for (int j = 0; j < 4; ++j) bcol[j] = bias[n0 + wn + j*16 + lm];
  STAGE_STORE(f2bf(acc[i][j][r] + bcol[j]))
}

// ---------------- gemm_nb: C = bf16(A[Mx256] @ WT[256-rows][256]), no bias, staged store ----------------
__global__ __launch_bounds__(256) void gemm_nb_kernel(const u16* __restrict__ A, const u16* __restrict__ WT,
    u16* __restrict__ C, int M){
  __shared__ u16 smem[10240];
  u16* As = smem; u16* Bs = smem + 5120;
  int m0 = blockIdx.x * 128, n0 = blockIdx.y * 128;
  if (m0 >= M) return;
  int t = threadIdx.x;
  int w = t >> 6, lane = t & 63;
  int wm = (w >> 1) << 6, wn = (w & 1) << 6;
  int lm = lane & 15;
  int lk = (lane >> 4) << 3;
  f32x4 acc[4][4] = {};
  int sr0 = t >> 2, sk0 = (t & 3) << 3;
  int sr1 = sr0 + 64;
  for (int k0 = 0; k0 < 256; k0 += 32){
    uint4 a0 = *(const uint4*)(A  + (size_t)(m0+sr0)*256 + k0 + sk0);
    uint4 a1 = *(const uint4*)(A  + (size_t)(m0+sr1)*256 + k0 + sk0);
    uint4 b0 = *(const uint4*)(WT + (size_t)(n0+sr0)*256 + k0 + sk0);
    uint4 b1 = *(const uint4*)(WT + (size_t)(n0+sr1)*256 + k0 + sk0);
    *(uint4*)&As[sr0*40 + sk0] = a0;
    *(uint4*)&As[sr1*40 + sk0] = a1;
    *(uint4*)&Bs[sr0*40 + sk0] = b0;
    *(uint4*)&Bs[sr1*40 + sk0] = b1;
    __syncthreads();
    bf16x8 af[4], bf[4];
    #pragma unroll
    for (int i = 0; i < 4; ++i) af[i] = *(const bf16x8*)&As[(wm + i*16 + lm)*40 + lk];
    #pragma unroll
    for (int j = 0; j < 4; ++j) bf[j] = *(const bf16x8*)&Bs[(wn + j*16 + lm)*40 + lk];
    #pragma unroll
    for (int i = 0; i < 4; ++i)
      #pragma unroll
      for (int j = 0; j < 4; ++j)
        acc[i][j] = __builtin_amdgcn_mfma_f32_16x16x32_bf16(af[i], bf[j], acc[i][j], 0, 0, 0);
    __syncthreads();
  }
  STAGE_STORE(f2bf(acc[i][j][r]))
}

// ---------------- batched transform GEMM (z=0: Tu=XU@W0T, z=1: Tm=XM@W2T), staged store ----------------
__global__ __launch_bounds__(256) void pair_gemm_kernel(
    const u16* __restrict__ A0, const u16* __restrict__ W0, u16* __restrict__ C0, int M0,
    const u16* __restrict__ A1, const u16* __restrict__ W1, u16* __restrict__ C1, int M1){
  int z = blockIdx.z;
  const u16* A = z ? A1 : A0;
  const u16* WT = z ? W1 : W0;
  u16* C = z ? C1 : C0;
  int M = z ? M1 : M0;
  int m0 = blockIdx.x * 128, n0 = blockIdx.y * 128;
  if (m0 >= M) return;
  __shared__ u16 smem[10240];
  u16* As = smem; u16* Bs = smem + 5120;
  int t = threadIdx.x;
  int w = t >> 6, lane = t & 63;
  int wm = (w >> 1) << 6, wn = (w & 1) << 6;
  int lm = lane & 15;
  int lk = (lane >> 4) << 3;
  f32x4 acc[4][4] = {};
  int sr0 = t >> 2, sk0 = (t & 3) << 3;
  int sr1 = sr0 + 64;
  for (int k0 = 0; k0 < 256; k0 += 32){
    uint4 a0 = *(const uint4*)(A  + (size_t)(m0+sr0)*256 + k0 + sk0);
    uint4 a1 = *(const uint4*)(A  + (size_t)(m0+sr1)*256 + k0 + sk0);
    uint4 b0 = *(const uint4*)(WT + (size_t)(n0+sr0)*256 + k0 + sk0);
    uint4 b1 = *(const uint4*)(WT + (size_t)(n0+sr1)*256 + k0 + sk0);
    *(uint4*)&As[sr0*40 + sk0] = a0;
    *(uint4*)&As[sr1*40 + sk0] = a1;
    *(uint4*)&Bs[sr0*40 + sk0] = b0;
    *(uint4*)&Bs[sr1*40 + sk0] = b1;
    __syncthreads();
    bf16x8 af[4], bf[4];
    #pragma unroll
    for (int i = 0; i < 4; ++i) af[i] = *(const bf16x8*)&As[(wm + i*16 + lm)*40 + lk];
    #pragma unroll
    for (int j = 0; j < 4; ++j) bf[j] = *(const bf16x8*)&Bs[(wn + j*16 + lm)*40 + lk];
    #pragma unroll
    for (int i = 0; i < 4; ++i)
      #pragma unroll
      for (int j = 0; j < 4; ++j)
        acc[i][j] = __builtin_amdgcn_mfma_f32_16x16x32_bf16(af[i], bf[j], acc[i][j], 0, 0, 0);
    __syncthreads();
  }
  STAGE_STORE(f2bf(acc[i][j][r]))
}

// ---------------- batched update GEMM: X_new = bf16(relu(AGG@Wa + Xold@Wb + b)), K=512, staged store ----
__global__ __launch_bounds__(256) void pair_gemm2_kernel(
    const u16* __restrict__ G0, const u16* __restrict__ X0, const u16* __restrict__ Wa0, const u16* __restrict__ Wb0,
    const float* __restrict__ b0, u16* __restrict__ C0, int M0,
    const u16* __restrict__ G1, const u16* __restrict__ X1, const u16* __restrict__ Wa1, const u16* __restrict__ Wb1,
    const float* __restrict__ b1, u16* __restrict__ C1, int M1){
  int z = blockIdx.z;
  const u16* G  = z ? G1 : G0;
  const u16* X  = z ? X1 : X0;
  const u16* Wa = z ? Wa1 : Wa0;
  const u16* Wb = z ? Wb1 : Wb0;
  const float* bias = z ? b1 : b0;
  u16* C = z ? C1 : C0;
  int M = z ? M1 : M0;
  int m0 = blockIdx.x * 128, n0 = blockIdx.y * 128;
  if (m0 >= M) return;
  __shared__ u16 smem[10240];
  u16* As = smem; u16* Bs = smem + 5120;
  int t = threadIdx.x;
  int w = t >> 6, lane = t & 63;
  int wm = (w >> 1) << 6, wn = (w & 1) << 6;
  int lm = lane & 15;
  int lk = (lane >> 4) << 3;
  f32x4 acc[4][4] = {};
  int sr0 = t >> 2, sk0 = (t & 3) << 3;
  int sr1 = sr0 + 64;
  for (int k0 = 0; k0 < 512; k0 += 32){
    const u16* A  = (k0 < 256) ? G : X;
    const u16* WT = (k0 < 256) ? Wa : Wb;
    int kk = k0 & 255;
    uint4 a0 = *(const uint4*)(A  + (size_t)(m0+sr0)*256 + kk + sk0);
    uint4 a1 = *(const uint4*)(A  + (size_t)(m0+sr1)*256 + kk + sk0);
    uint4 b0_ = *(const uint4*)(WT + (size_t)(n0+sr0)*256 + kk + sk0);
    uint4 b1_ = *(const uint4*)(WT + (size_t)(n0+sr1)*256 + kk + sk0);
    *(uint4*)&As[sr0*40 + sk0] = a0;
    *(uint4*)&As[sr1*40 + sk0] = a1;
    *(uint4*)&Bs[sr0*40 + sk0] = b0_;
    *(uint4*)&Bs[sr1*40 + sk0] = b1_;
    __syncthreads();
    bf16x8 af[4], bf[4];
    #pragma unroll
    for (int i = 0; i < 4; ++i) af[i] = *(const bf16x8*)&As[(wm + i*16 + lm)*40 + lk];
    #pragma unroll
    for (int j = 0; j < 4; ++j) bf[j] = *(const bf16x8*)&Bs[(wn + j*16 + lm)*40 + lk];
    #pragma unroll
    for (int i = 0; i < 4; ++i)
      #pragma unroll
      for (int j = 0; j < 4; ++j)
        acc[i][j] = __builtin_amdgcn_mfma_f32_16x16x32_bf16(af[i], bf[j], acc[i][j], 0, 0, 0);
    __syncthreads();
  }
  float bcol[4];
  #pragma unroll
  for (int j = 0; j < 4; ++j) bcol[j] = bias[n0 + wn + j*16 + lm];
  STAGE_STORE(f2bf(fmaxf(acc[i][j][r] + bcol[j], 0.f)))
}

// ---------------- batched gather-mean (y=0: tm -> AGGM, y=1: tu -> AGGU) ----------------
__global__ __launch_bounds__(256) void gather_pair_kernel(const u16* __restrict__ XT,
    const int* __restrict__ rp0, const int* __restrict__ ss0, const float* __restrict__ inv0,
    u16* __restrict__ out0, int M0,
    const int* __restrict__ rp1, const int* __restrict__ ss1, const float* __restrict__ inv1,
    u16* __restrict__ out1, int M1){
  int y = blockIdx.y;
  const int* rp = y ? rp1 : rp0;
  const int* ss = y ? ss1 : ss0;
  const float* inv = y ? inv1 : inv0;
  u16* out = y ? out1 : out0;
  int M = y ? M1 : M0;
  int d = blockIdx.x*4 + (threadIdx.x >> 6);
  if (d >= M) return;
  int lane = threadIdx.x & 63;
  int c = lane << 2;
  float o0=0,o1=0,o2=0,o3=0;
  gather4(XT, ss, rp[d], rp[d+1], lane, c, o0, o1, o2, o3);
  float sc = inv[d];
  ushort4 o; o.x = f2bf(o0*sc); o.y = f2bf(o1*sc); o.z = f2bf(o2*sc); o.w = f2bf(o3*sc);
  *(ushort4*)(out + (size_t)d*HD + c) = o;
}

// ---------------- fused tx epilogue (1 row/wave, 64 lanes x 8B) ----------------
__global__ __launch_bounds__(256) void fused_tx_kernel(const u16* __restrict__ ACCb,
    const u16* __restrict__ Tu, const u16* __restrict__ Tm,
    const int* __restrict__ rpu, const int* __restrict__ ssu, const float* __restrict__ invu,
    const int* __restrict__ rpm, const int* __restrict__ ssm, const float* __restrict__ invm,
    const float* __restrict__ b0, const float* __restrict__ b2, u16* __restrict__ XT, int M){
  int d = blockIdx.x*4 + (threadIdx.x >> 6);
  if (d >= M) return;
  int lane = threadIdx.x & 63;
  int c = lane << 2;
  ushort4 av = *(const ushort4*)(ACCb + (size_t)d*HD + c);
  float r0 = bf2f(av.x), r1 = bf2f(av.y), r2 = bf2f(av.z), r3 = bf2f(av.w);
  {
    float s0=0,s1=0,s2=0,s3=0;
    gather4(Tu, ssu, rpu[d], rpu[d+1], lane, c, s0, s1, s2, s3);
    float sc = invu[d];
    r0 += s0*sc; r1 += s1*sc; r2 += s2*sc; r3 += s3*sc;
  }
  {
    float s0=0,s1=0,s2=0,s3=0;
    gather4(Tm, ssm, rpm[d], rpm[d+1], lane, c, s0, s1, s2, s3);
    float sc = invm[d];
    r0 += s0*sc; r1 += s1*sc; r2 += s2*sc; r3 += s3*sc;
  }
  float4 bb0 = *(const float4*)(b0 + c);
  float4 bb2 = *(const float4*)(b2 + c);
  ushort4 o;
  o.x = f2bf(fmaxf(0.5f*(r0 + bb0.x + bb2.x), 0.f));
  o.y = f2bf(fmaxf(0.5f*(r1 + bb0.y + bb2.y), 0.f));
  o.z = f2bf(fmaxf(0.5f*(r2 + bb0.z + bb2.z), 0.f));
  o.w = f2bf(fmaxf(0.5f*(r3 + bb0.w + bb2.w), 0.f));
  *(ushort4*)(XT + (size_t)d*HD + c) = o;
}

// ---------------- fused head: out = (relu(XT@[Wc1|Wv1]+bH)) @ {Wc2|Wv2} + {bc2|bv2} ----------------
__global__ __launch_bounds__(256) void fused_head_kernel(const u16* __restrict__ A, const u16* __restrict__ BT,
    const float* __restrict__ bias, const float* __restrict__ Wc2, const float* __restrict__ bc2,
    const float* __restrict__ Wv2, const float* __restrict__ bv2, float* __restrict__ out, int M){
  __shared__ u16 As[128*40];
  __shared__ u16 Bs[128*40];
  __shared__ float hpart[128];
  int m0 = blockIdx.x * 128, n0 = blockIdx.y * 128;
  int t = threadIdx.x;
  int w = t >> 6, lane = t & 63;
  int wm = (w >> 1) << 6, wn = (w & 1) << 6;
  int lm = lane & 15;
  int lk = (lane >> 4) << 3;
  if (t < 128) hpart[t] = 0.f;
  f32x4 acc[4][4] = {};
  int sr0 = t >> 2, sk0 = (t & 3) << 3;
  int sr1 = sr0 + 64;
  for (int k0 = 0; k0 < 256; k0 += 32){
    uint4 a0 = *(const uint4*)(A  + (size_t)(m0+sr0)*256 + k0 + sk0);
    uint4 a1 = *(const uint4*)(A  + (size_t)(m0+sr1)*256 + k0 + sk0);
    uint4 b0 = *(const uint4*)(BT + (size_t)(n0+sr0)*256 + k0 + sk0);
    uint4 b1 = *(const uint4*)(BT + (size_t)(n0+sr1)*256 + k0 + sk0);
    *(uint4*)&As[sr0*40 + sk0] = a0;
    *(uint4*)&As[sr1*40 + sk0] = a1;
    *(uint4*)&Bs[sr0*40 + sk0] = b0;
    *(uint4*)&Bs[sr1*40 + sk0] = b1;
    __syncthreads();
    bf16x8 af[4], bf[4];
    #pragma unroll
    for (int i = 0; i < 4; ++i) af[i] = *(const bf16x8*)&As[(wm + i*16 + lm)*40 + lk];
    #pragma unroll
    for (int j = 0; j < 4; ++j) bf[j] = *(const bf16x8*)&Bs[(wn + j*16 + lm)*40 + lk];
    #pragma unroll
    for (int i = 0; i < 4; ++i)
      #pragma unroll
      for (int j = 0; j < 4; ++j)
        acc[i][j] = __builtin_amdgcn_mfma_f32_16x16x32_bf16(af[i], bf[j], acc[i][j], 0, 0, 0);
    __syncthreads();
  }
  const float* w2 = blockIdx.y ? Wv2 : Wc2;
  float badd = blockIdx.y ? bv2[0] : bc2[0];
  size_t outoff = blockIdx.y ? (size_t)M : 0;
  int rsub = (lane >> 4) << 2;
  float w2v[4], bv[4];
  #pragma unroll
  for (int j = 0; j < 4; ++j){
    w2v[j] = w2[wn + j*16 + lm];
    bv[j]  = bias[n0 + wn + j*16 + lm];
  }
  #pragma unroll
  for (int i = 0; i < 4; ++i){
    #pragma unroll
    for (int r = 0; r < 4; ++r){
      float p = 0.f;
      #pragma unroll
      for (int j = 0; j < 4; ++j) p += fmaxf(acc[i][j][r] + bv[j], 0.f) * w2v[j];
      p += __shfl_xor(p, 1); p += __shfl_xor(p, 2);
      p += __shfl_xor(p, 4); p += __shfl_xor(p, 8);
      if (lm == 0) atomicAdd(&hpart[wm + i*16 + rsub + r], p);
    }
  }
  __syncthreads();
  if (t < 128){
    int row = m0 + t;
    if (row < M) out[outoff + row] = hpart[t] + badd;
  }
}

extern "C" void kernel_launch(void* const* d_in, const int* in_sizes, int n_in,
                              void* d_out, int out_size, void* d_ws, size_t ws_size,
                              hipStream_t stream){
  const float* x_tx   = (const float*)d_in[0];
  const float* x_user = (const float*)d_in[1];
  const float* x_merch= (const float*)d_in[2];
  const float* Wp  = (const float*)d_in[3];
  const float* bp  = (const float*)d_in[4];
  const float* Wl  = (const float*)d_in[5];
  const float* bl  = (const float*)d_in[6];
  const float* Wr  = (const float*)d_in[7];
  const float* Wc1 = (const float*)d_in[8];
  const float* bc1 = (const float*)d_in[9];
  const float* Wc2 = (const float*)d_in[10];
  const float* bc2 = (const float*)d_in[11];
  const float* Wv1 = (const float*)d_in[12];
  const float* bv1 = (const float*)d_in[13];
  const float* Wv2 = (const float*)d_in[14];
  const float* bv2 = (const float*)d_in[15];
  const int* e_ut_s = (const int*)d_in[16];
  const int* e_ut_d = (const int*)d_in[17];
  const int* e_tm_s = (const int*)d_in[18];
  const int* e_tm_d = (const int*)d_in[19];
  const int* e_mt_s = (const int*)d_in[20];
  const int* e_mt_d = (const int*)d_in[21];
  const int* e_tu_s = (const int*)d_in[22];
  const int* e_tu_d = (const int*)d_in[23];
  float* out = (float*)d_out;
  const int NE = in_sizes[16];

  // ---- workspace layout (~176 MB) ----
  char* p = (char*)d_ws;
  auto take = [&](size_t bytes)->char*{ char* r = p; p += (bytes + 255) & ~(size_t)255; return r; };
  u16*   XT    = (u16*)  take((size_t)(NTX+ROWPAD)*HD*2);
  u16*   ACCb  = (u16*)  take((size_t)(NTX+ROWPAD)*HD*2);
  u16*   Tu    = (u16*)  take((size_t)NUSER*HD*2);
  u16*   Tm    = (u16*)  take((size_t)NMERCH*HD*2);
  u16*   AGGU  = (u16*)  take((size_t)(NUSER+ROWPAD)*HD*2);
  u16*   AGGM  = (u16*)  take((size_t)(NMERCH+ROWPAD)*HD*2);
  u16*   XU0   = (u16*)  take((size_t)(NUSER+ROWPAD)*HD*2);
  u16*   XU1   = (u16*)  take((size_t)(NUSER+ROWPAD)*HD*2);
  u16*   XM0   = (u16*)  take((size_t)(NMERCH+ROWPAD)*HD*2);
  u16*   XM1   = (u16*)  take((size_t)(NMERCH+ROWPAD)*HD*2);
  float* INV   = (float*)take((size_t)225000*4);
  int*   RP    = (int*)  take((size_t)225008*4);
  int*   SS_ut = (int*)  take((size_t)NE*4);
  int*   SS_tm = (int*)  take((size_t)NE*4);
  int*   SS_mt = (int*)  take((size_t)NE*4);
  int*   SS_tu = (int*)  take((size_t)NE*4);
  int*   PC    = (int*)  take((size_t)4*ECH*64*4);
  int*   PST   = (int*)  take((size_t)4*PSTW*4);
  int*   EB    = (int*)  take((size_t)4*NE*4);
  u16*   WTp   = (u16*)  take((size_t)32*256*2);
  u16*   WTl   = (u16*)  take((size_t)8*65536*2);
  u16*   WTr1  = (u16*)  take((size_t)2*65536*2);
  u16*   WTr3  = (u16*)  take((size_t)2*65536*2);
  u16*   WT02  = (u16*)  take((size_t)2*65536*2);
  u16*   WTH   = (u16*)  take((size_t)65536*2);
  float* bH    = (float*)take((size_t)256*4);

  float* inv_ut = INV,  *inv_tm = INV+100000, *inv_mt = INV+105000, *inv_tu = INV+205000;
  int*   rp_ut  = RP,   *rp_tm  = RP+100001,  *rp_mt  = RP+105002,  *rp_tu  = RP+205003;

  // ---- CSR build: radix partition ----
  csrA_kernel<<<dim3(ECH,4),256,0,stream>>>(e_ut_d, e_tm_d, e_mt_d, e_tu_d, NE, PC);
  csrB_kernel<<<dim3(1,4),64,0,stream>>>(PC, PST, RP, NE);
  csrC_kernel<<<dim3(ECH,4),256,0,stream>>>(e_ut_s, e_ut_d, e_tm_s, e_tm_d, e_mt_s, e_mt_d,
      e_tu_s, e_tu_d, PC, EB, NE);
  csrD_kernel<<<dim3(49,4),256,0,stream>>>(EB, PST, RP, INV, SS_ut, SS_tm, SS_mt, SS_tu, NE);

  // ---- weight prep ----
  wprep_kernel<<<dim3(256,16),256,0,stream>>>(Wl, Wr, Wp, Wc1, Wv1, bc1, bv1,
      WTl, WTr1, WTr3, WT02, WTH, WTp, bH);

  // ---- init activations ----
  cvt2_kernel<<<dim3(5000,2),256,0,stream>>>(x_user, x_merch, XU0, XM0);
  proj_gemm_kernel<<<dim3(782,2),256,0,stream>>>(x_tx, WTp, bp, XT, NTX);

  u16* xu_cur = XU0; u16* xu_nxt = XU1;
  u16* xm_cur = XM0; u16* xm_nxt = XM1;

  for (int l = 0; l < 2; ++l){
    const float* bl_l = bl + (size_t)l*4*256;
    u16* WTl_l = WTl + (size_t)l*4*65536;

    // inbound means of OLD XT into merchant/user (batched)
    gather_pair_kernel<<<dim3(5000,2),256,0,stream>>>(XT,
        rp_tm, SS_tm, inv_tm, AGGM, NMERCH,
        rp_tu, SS_tu, inv_tu, AGGU, NUSER);

    // transform-first for tx inbound (batched: Tu = XU@Wl0, Tm = XM@Wl2)
    pair_gemm_kernel<<<dim3(157,2,2),256,0,stream>>>(
        xu_cur, WTl_l + 0*65536, Tu, NUSER,
        xm_cur, WTl_l + 2*65536, Tm, NMERCH);

    // tx root term + fused epilogue -> new XT (in place; all reads of old XT done)
    gemm_nb_kernel<<<dim3(782,2),256,0,stream>>>(XT, WT02 + (size_t)l*65536, ACCb, NTX);
    fused_tx_kernel<<<(NTX+3)/4,256,0,stream>>>(ACCb, Tu, Tm,
        rp_ut, SS_ut, inv_ut, rp_mt, SS_mt, inv_mt,
        bl_l + 0*256, bl_l + 2*256, XT, NTX);

    // user/merchant updates (batched, virtual K=512, fused bias+relu+bf16)
    pair_gemm2_kernel<<<dim3(157,2,2),256,0,stream>>>(
        AGGU, xu_cur, WTl_l + 3*65536, WTr3 + (size_t)l*65536, bl_l + 3*256, xu_nxt, NUSER,
        AGGM, xm_cur, WTl_l + 1*65536, WTr1 + (size_t)l*65536, bl_l + 1*256, xm_nxt, NMERCH);

    { u16* tmp = xu_cur; xu_cur = xu_nxt; xu_nxt = tmp; }
    { u16* tmp = xm_cur; xm_cur = xm_nxt; xm_nxt = tmp; }
  }

  // fused heads (direct out write)
  fused_head_kernel<<<dim3(782,2),256,0,stream>>>(XT, WTH, bH, Wc2, bc2, Wv2, bv2, out, NTX);
}

// Round 18
// 512.236 us; speedup vs baseline: 1.2612x; 1.0585x over previous
//
#include <hip/hip_runtime.h>

#define NTX 100000
#define NUSER 20000
#define NMERCH 5000
#define HD 256
#define ROWPAD 128

using u16 = unsigned short;
typedef __attribute__((ext_vector_type(8))) short bf16x8;
typedef __attribute__((ext_vector_type(4))) float f32x4;

__device__ __forceinline__ u16 f2bf(float f){
  unsigned u = __float_as_uint(f);
  unsigned r = (u + 0x7FFFu + ((u >> 16) & 1u)) >> 16;
  return (u16)r;
}
__device__ __forceinline__ float bf2f(u16 b){
  return __uint_as_float(((unsigned)b) << 16);
}
__device__ __forceinline__ unsigned pk2(float a, float b){
  return (unsigned)f2bf(a) | ((unsigned)f2bf(b) << 16);
}

// full-row gather (8B/lane, 64 lanes per row): cooperative index load + shfl + 4 chains.
// 28 VGPR / ~70% occupancy — measured best point.
__device__ __forceinline__ void gather4(const u16* __restrict__ T, const int* __restrict__ ss,
    int j0, int j1, int lane, int c, float& o0, float& o1, float& o2, float& o3){
  float a0=0,a1=0,a2=0,a3=0, b0=0,b1=0,b2=0,b3=0;
  float c0=0,c1=0,c2=0,c3=0, d0=0,d1=0,d2=0,d3=0;
  for (int base = j0; base < j1; base += 64){
    int n = j1 - base; if (n > 64) n = 64;
    int idx = ss[base + (lane < n ? lane : 0)];
    for (int jj = 0; jj < n; jj += 4){
      int s0 = __shfl(idx, jj);
      int s1 = __shfl(idx, jj+1);
      int s2 = __shfl(idx, jj+2);
      int s3 = __shfl(idx, jj+3);
      ushort4 v0 = *(const ushort4*)(T + (size_t)s0*HD + c);
      ushort4 v1 = *(const ushort4*)(T + (size_t)s1*HD + c);
      ushort4 v2 = *(const ushort4*)(T + (size_t)s2*HD + c);
      ushort4 v3 = *(const ushort4*)(T + (size_t)s3*HD + c);
      a0 += bf2f(v0.x); a1 += bf2f(v0.y); a2 += bf2f(v0.z); a3 += bf2f(v0.w);
      if (jj+1 < n){ b0 += bf2f(v1.x); b1 += bf2f(v1.y); b2 += bf2f(v1.z); b3 += bf2f(v1.w); }
      if (jj+2 < n){ c0 += bf2f(v2.x); c1 += bf2f(v2.y); c2 += bf2f(v2.z); c3 += bf2f(v2.w); }
      if (jj+3 < n){ d0 += bf2f(v3.x); d1 += bf2f(v3.y); d2 += bf2f(v3.z); d3 += bf2f(v3.w); }
    }
  }
  o0 += (a0+b0)+(c0+d0); o1 += (a1+b1)+(c1+d1);
  o2 += (a2+b2)+(c2+d2); o3 += (a3+b3)+(c3+d3);
}

// ---------------- CSR radix-partition build (blockIdx.y = relation: 0=ut,1=tm,2=mt,3=tu) ----------------
__device__ __forceinline__ int rel_n(int y){ return y==0?NTX: y==1?NMERCH: y==2?NTX:NUSER; }
__device__ __forceinline__ int rel_coff(int y){ return y==0?0: y==1?100000: y==2?105000:205000; }
__device__ __forceinline__ int rel_rpoff(int y){ return y==0?0: y==1?100001: y==2?105002:205003; }
__device__ __forceinline__ int rel_shift(int y){ return y==0?11: y==1?8: y==2?11:10; }
__device__ __forceinline__ int rel_np(int y){ return y==0?49: y==1?20: y==2?49:20; }
#define ECH 128
#define PSTW 72

__global__ __launch_bounds__(256) void csrA_kernel(const int* __restrict__ d0p, const int* __restrict__ d1p,
    const int* __restrict__ d2p, const int* __restrict__ d3p, int nE, int* __restrict__ PC){
  int y = blockIdx.y;
  const int* dst = y==0?d0p: y==1?d1p: y==2?d2p:d3p;
  int shift = rel_shift(y);
  __shared__ int cc[64];
  int t = threadIdx.x;
  if (t < 64) cc[t] = 0;
  __syncthreads();
  int CH = (nE + ECH - 1)/ECH;
  int e0 = blockIdx.x*CH, e1 = e0 + CH; if (e1 > nE) e1 = nE;
  for (int e = e0 + t*4; e < e1; e += 1024){
    int a = dst[e];
    int b = (e+1 < e1) ? dst[e+1] : -1;
    int c = (e+2 < e1) ? dst[e+2] : -1;
    int d = (e+3 < e1) ? dst[e+3] : -1;
    atomicAdd(&cc[a>>shift], 1);
    if (b >= 0) atomicAdd(&cc[b>>shift], 1);
    if (c >= 0) atomicAdd(&cc[c>>shift], 1);
    if (d >= 0) atomicAdd(&cc[d>>shift], 1);
  }
  __syncthreads();
  if (t < 64) PC[(((size_t)y*ECH + blockIdx.x)<<6) + t] = cc[t];
}

__global__ void csrB_kernel(int* __restrict__ PC, int* __restrict__ PST, int* __restrict__ RP, int nE){
  int y = blockIdx.y;
  int np = rel_np(y);
  int t = threadIdx.x;
  __shared__ int sh[64];
  int run = 0;
  if (t < np){
    for (int c = 0; c < ECH; ++c){
      size_t idx = (((size_t)y*ECH + c)<<6) + t;
      int v = PC[idx]; PC[idx] = run; run += v;
    }
  }
  sh[t] = run;
  __syncthreads();
  if (t == 0){
    int acc = 0;
    for (int i = 0; i < np; ++i){ int v = sh[i]; sh[i] = acc; acc += v; }
    PST[y*PSTW + np] = nE;
    RP[rel_rpoff(y) + rel_n(y)] = nE;
  }
  __syncthreads();
  if (t < np){
    int base = sh[t];
    PST[y*PSTW + t] = base;
    for (int c = 0; c < ECH; ++c){
      size_t idx = (((size_t)y*ECH + c)<<6) + t;
      PC[idx] += base;
    }
  }
}

__global__ __launch_bounds__(256) void csrC_kernel(
    const int* __restrict__ s0p, const int* __restrict__ d0p,
    const int* __restrict__ s1p, const int* __restrict__ d1p,
    const int* __restrict__ s2p, const int* __restrict__ d2p,
    const int* __restrict__ s3p, const int* __restrict__ d3p,
    const int* __restrict__ PC, int* __restrict__ EB, int nE){
  int y = blockIdx.y;
  const int* src = y==0?s0p: y==1?s1p: y==2?s2p:s3p;
  const int* dst = y==0?d0p: y==1?d1p: y==2?d2p:d3p;
  int shift = rel_shift(y);
  int mask = (1<<shift) - 1;
  __shared__ int cur[64];
  int t = threadIdx.x;
  if (t < 64) cur[t] = PC[(((size_t)y*ECH + blockIdx.x)<<6) + t];
  __syncthreads();
  int CH = (nE + ECH - 1)/ECH;
  int e0 = blockIdx.x*CH, e1 = e0 + CH; if (e1 > nE) e1 = nE;
  int* eb = EB + (size_t)y*nE;
  for (int e = e0 + t*4; e < e1; e += 1024){
    #pragma unroll
    for (int u = 0; u < 4; ++u){
      int ee = e + u;
      if (ee < e1){
        int d = dst[ee], s = src[ee];
        int pos = atomicAdd(&cur[d>>shift], 1);
        eb[pos] = ((d & mask) << 17) | s;
      }
    }
  }
}

__global__ __launch_bounds__(256) void csrD_kernel(const int* __restrict__ EB, const int* __restrict__ PST,
    int* __restrict__ RP, float* __restrict__ INV,
    int* __restrict__ ss0, int* __restrict__ ss1, int* __restrict__ ss2, int* __restrict__ ss3, int nE){
  int y = blockIdx.y;
  int np = rel_np(y);
  int part = blockIdx.x;
  if (part >= np) return;
  int shift = rel_shift(y);
  int n = rel_n(y);
  int gbase = part << shift;
  int len = n - gbase; int range = 1 << shift; if (len > range) len = range;
  __shared__ int cnt[2048];
  __shared__ int curs[2048];
  __shared__ int sh[256];
  int t = threadIdx.x;
  for (int i = t; i < len; i += 256) cnt[i] = 0;
  __syncthreads();
  const int* eb = EB + (size_t)y*nE;
  int j0 = PST[y*PSTW + part], j1 = PST[y*PSTW + part + 1];
  for (int j = j0 + t*4; j < j1; j += 1024){
    int a = eb[j];
    int b = (j+1 < j1) ? eb[j+1] : -1;
    int c = (j+2 < j1) ? eb[j+2] : -1;
    int d = (j+3 < j1) ? eb[j+3] : -1;
    atomicAdd(&cnt[a>>17], 1);
    if (b >= 0) atomicAdd(&cnt[b>>17], 1);
    if (c >= 0) atomicAdd(&cnt[c>>17], 1);
    if (d >= 0) atomicAdd(&cnt[d>>17], 1);
  }
  __syncthreads();
  int base8 = t*8;
  int vals[8]; int tsum = 0;
  #pragma unroll
  for (int u = 0; u < 8; ++u){
    int i = base8 + u;
    int v = (i < len) ? cnt[i] : 0;
    vals[u] = tsum; tsum += v;
  }
  sh[t] = tsum;
  __syncthreads();
  for (int o = 1; o < 256; o <<= 1){
    int v = (t >= o) ? sh[t-o] : 0;
    __syncthreads();
    sh[t] += v;
    __syncthreads();
  }
  int tbase = j0 + sh[t] - tsum;
  int rpo = rel_rpoff(y) + gbase;
  int ivo = rel_coff(y) + gbase;
  #pragma unroll
  for (int u = 0; u < 8; ++u){
    int i = base8 + u;
    if (i < len){
      int start = tbase + vals[u];
      curs[i] = start;
      RP[rpo + i] = start;
      INV[ivo + i] = 1.f/fmaxf((float)cnt[i], 1.f);
    }
  }
  __syncthreads();
  int* ss = y==0?ss0: y==1?ss1: y==2?ss2:ss3;
  for (int j = j0 + t*4; j < j1; j += 1024){
    #pragma unroll
    for (int u = 0; u < 4; ++u){
      int jj = j + u;
      if (jj < j1){
        int pk = eb[jj];
        int pos = atomicAdd(&curs[pk>>17], 1);
        ss[pos] = pk & 0x1FFFF;
      }
    }
  }
}

// ---------------- fused weight prep (grid.y = 0..15) ----------------
__global__ __launch_bounds__(256) void wprep_kernel(const float* __restrict__ Wl, const float* __restrict__ Wr,
    const float* __restrict__ Wp, const float* __restrict__ Wc1, const float* __restrict__ Wv1,
    const float* __restrict__ bc1, const float* __restrict__ bv1,
    u16* __restrict__ WTl, u16* __restrict__ WTr1, u16* __restrict__ WTr3, u16* __restrict__ WT02,
    u16* __restrict__ WTH, u16* __restrict__ WTp, float* __restrict__ bH){
  int y = blockIdx.y;
  int i = blockIdx.x*256 + threadIdx.x;
  if (y < 8){
    if (i < 65536){ int k=i>>8, n=i&255; WTl[(size_t)y*65536 + n*256 + k] = f2bf(Wl[(size_t)y*65536 + i]); }
  } else if (y < 10){
    int l = y-8;
    if (i < 65536){ int k=i>>8, n=i&255; WTr1[(size_t)l*65536 + n*256 + k] = f2bf(Wr[(size_t)(l*4+1)*65536 + i]); }
  } else if (y < 12){
    int l = y-10;
    if (i < 65536){ int k=i>>8, n=i&255; WTr3[(size_t)l*65536 + n*256 + k] = f2bf(Wr[(size_t)(l*4+3)*65536 + i]); }
  } else if (y < 14){
    int l = y-12;
    if (i < 65536){ int k=i>>8, n=i&255;
      WT02[(size_t)l*65536 + n*256 + k] = f2bf(Wr[(size_t)(l*4+0)*65536 + i] + Wr[(size_t)(l*4+2)*65536 + i]); }
  } else if (y == 14){
    if (i < 65536){ int k=i>>8, n=i&255;
      float v = (n < 128) ? Wc1[k*128 + n] : Wv1[k*128 + (n-128)];
      WTH[(size_t)n*256 + k] = f2bf(v); }
  } else {
    if (i < 8192){ int k=i>>8, n=i&255; WTp[(size_t)n*32 + k] = f2bf(Wp[i]); }
    if (i < 256) bH[i] = (i < 128) ? bc1[i] : bv1[i-128];
  }
}

// fused f32->bf16 conversions (y=0: x_user, y=1: x_merch)
__global__ __launch_bounds__(256) void cvt2_kernel(const float* __restrict__ xu,
    const float* __restrict__ xm, u16* __restrict__ XU, u16* __restrict__ XM){
  int y = blockIdx.y;
  const float* in = y==0?xu:xm;
  u16* out = y==0?XU:XM;
  int n4 = y==0?NUSER*HD/4:NMERCH*HD/4;
  int i = blockIdx.x*256 + threadIdx.x;
  if (i >= n4) return;
  float4 v = ((const float4*)in)[i];
  ushort4 o; o.x = f2bf(v.x); o.y = f2bf(v.y); o.z = f2bf(v.z); o.w = f2bf(v.w);
  ((ushort4*)out)[i] = o;
}

// ---- shared staged-store epilogue: stage bf16 rows into LDS, store coalesced uint4 ----
#define STAGE_STORE(EXPR_BF16)                                                     \
  {                                                                                \
    int rsub = (lane >> 4) << 2;                                                   \
    int wh = w >> 1;                                                               \
    for (int h = 0; h < 2; ++h){                                                   \
      if (wh == h){                                                                \
        _Pragma("unroll")                                                          \
        for (int j = 0; j < 4; ++j){                                               \
          int cl = wn + j*16 + lm;                                                 \
          _Pragma("unroll")                                                        \
          for (int i = 0; i < 4; ++i){                                             \
            int lr = i*16 + rsub;                                                  \
            _Pragma("unroll")                                                      \
            for (int r = 0; r < 4; ++r) smem[(lr+r)*136 + cl] = (EXPR_BF16);       \
          }                                                                        \
        }                                                                          \
      }                                                                            \
      __syncthreads();                                                             \
      int lr2 = threadIdx.x >> 2;                                                  \
      int cb = (threadIdx.x & 3) << 5;                                             \
      int grow = m0 + h*64 + lr2;                                                  \
      if (grow < M){                                                               \
        _Pragma("unroll")                                                          \
        for (int kq = 0; kq < 4; ++kq)                                             \
          *(uint4*)(C + (size_t)grow*256 + n0 + cb + kq*8) =                       \
              *(const uint4*)&smem[lr2*136 + cb + kq*8];                           \
      }                                                                            \
      __syncthreads();                                                             \
    }                                                                              \
  }

// ---------------- proj GEMM: XT = bf16(x_tx[f32, Mx32] @ WTp[256x32] + bp), staged store ----------------
__global__ __launch_bounds__(256) void proj_gemm_kernel(const float* __restrict__ A, const u16* __restrict__ WT,
    const float* __restrict__ bias, u16* __restrict__ C, int M){
  __shared__ u16 smem[10240];
  u16* As = smem; u16* Bs = smem + 5120;
  int m0 = blockIdx.x * 128, n0 = blockIdx.y * 128;
  int t = threadIdx.x;
  int w = t >> 6, lane = t & 63;
  int wm = (w >> 1) << 6, wn = (w & 1) << 6;
  int lm = lane & 15;
  int lk = (lane >> 4) << 3;
  int sr = t >> 1, sc = (t & 1) << 4;
  float4 f0 = {0,0,0,0}, f1 = {0,0,0,0}, f2 = {0,0,0,0}, f3 = {0,0,0,0};
  if (m0 + sr < M){
    const float* ap = A + (size_t)(m0+sr)*32 + sc;
    f0 = *(const float4*)(ap+0); f1 = *(const float4*)(ap+4);
    f2 = *(const float4*)(ap+8); f3 = *(const float4*)(ap+12);
  }
  uint4 q0, q1;
  q0.x = pk2(f0.x,f0.y); q0.y = pk2(f0.z,f0.w); q0.z = pk2(f1.x,f1.y); q0.w = pk2(f1.z,f1.w);
  q1.x = pk2(f2.x,f2.y); q1.y = pk2(f2.z,f2.w); q1.z = pk2(f3.x,f3.y); q1.w = pk2(f3.z,f3.w);
  *(uint4*)&As[sr*40 + sc] = q0;
  *(uint4*)&As[sr*40 + sc+8] = q1;
  const u16* bp_ = WT + (size_t)(n0+sr)*32 + sc;
  *(uint4*)&Bs[sr*40 + sc]   = *(const uint4*)(bp_);
  *(uint4*)&Bs[sr*40 + sc+8] = *(const uint4*)(bp_ + 8);
  __syncthreads();
  bf16x8 af[4], bf[4];
  #pragma unroll
  for (int i = 0; i < 4; ++i) af[i] = *(const bf16x8*)&As[(wm + i*16 + lm)*40 + lk];
  #pragma unroll
  for (int j = 0; j < 4; ++j) bf[j] = *(const bf16x8*)&Bs[(wn + j*16 + lm)*40 + lk];
  f32x4 acc[4][4] = {};
  #pragma unroll
  for (int i = 0; i < 4; ++i)
    #pragma unroll
    for (int j = 0; j < 4; ++j)
      acc[i][j] = __builtin_amdgcn_mfma_f32_16x16x32_bf16(af[i], bf[j], acc[i][j], 0, 0, 0);
  __syncthreads();
  float bcol[4];
  #pragma unroll
  for (int j = 0; j < 4; ++j) bcol[j] = bias[n0 + wn + j*16 + lm];
  STAGE_STORE(f2bf(acc[i][j][r] + bcol[j]))
}

// ---------------- GEMM body: C = bf16(A[Mx256] @ WT[.][256]), no bias, staged store ----------------
__device__ __forceinline__ void gemm_nb_body(const u16* __restrict__ A, const u16* __restrict__ WT,
    u16* __restrict__ C, int M, int m0, int n0, u16* smem){
  u16* As = smem; u16* Bs = smem + 5120;
  int t = threadIdx.x;
  int w = t >> 6, lane = t & 63;
  int wm = (w >> 1) << 6, wn = (w & 1) << 6;
  int lm = lane & 15;
  int lk = (lane >> 4) << 3;
  f32x4 acc[4][4] = {};
  int sr0 = t >> 2, sk0 = (t & 3) << 3;
  int sr1 = sr0 + 64;
  for (int k0 = 0; k0 < 256; k0 += 32){
    uint4 a0 = *(const uint4*)(A  + (size_t)(m0+sr0)*256 + k0 + sk0);
    uint4 a1 = *(const uint4*)(A  + (size_t)(m0+sr1)*256 + k0 + sk0);
    uint4 b0 = *(const uint4*)(WT + (size_t)(n0+sr0)*256 + k0 + sk0);
    uint4 b1 = *(const uint4*)(WT + (size_t)(n0+sr1)*256 + k0 + sk0);
    *(uint4*)&As[sr0*40 + sk0] = a0;
    *(uint4*)&As[sr1*40 + sk0] = a1;
    *(uint4*)&Bs[sr0*40 + sk0] = b0;
    *(uint4*)&Bs[sr1*40 + sk0] = b1;
    __syncthreads();
    bf16x8 af[4], bf[4];
    #pragma unroll
    for (int i = 0; i < 4; ++i) af[i] = *(const bf16x8*)&As[(wm + i*16 + lm)*40 + lk];
    #pragma unroll
    for (int j = 0; j < 4; ++j) bf[j] = *(const bf16x8*)&Bs[(wn + j*16 + lm)*40 + lk];
    #pragma unroll
    for (int i = 0; i < 4; ++i)
      #pragma unroll
      for (int j = 0; j < 4; ++j)
        acc[i][j] = __builtin_amdgcn_mfma_f32_16x16x32_bf16(af[i], bf[j], acc[i][j], 0, 0, 0);
    __syncthreads();
  }
  STAGE_STORE(f2bf(acc[i][j][r]))
}

// ---------------- merged A: root GEMM + Tu/Tm transform GEMMs (all read old state) ----------------
// blocks: [0,1564) root (782 x-blocks x 2 n) | [1564,1878) user transform | [1878,1958) merch transform
__global__ __launch_bounds__(256) void gemmsA_kernel(
    const u16* __restrict__ XT, const u16* __restrict__ WT02l, u16* __restrict__ ACCb,
    const u16* __restrict__ xu, const u16* __restrict__ Wl0, u16* __restrict__ Tu,
    const u16* __restrict__ xm, const u16* __restrict__ Wl2, u16* __restrict__ Tm){
  __shared__ u16 smem[10240];
  int b = blockIdx.x;
  if (b < 1564){
    int ny = (b >= 782) ? 1 : 0;
    int x = b - ny*782;
    gemm_nb_body(XT, WT02l, ACCb, NTX, x*128, ny*128, smem);
  } else {
    int bb = b - 1564;
    if (bb < 314){
      int ny = bb / 157, x = bb - ny*157;
      gemm_nb_body(xu, Wl0, Tu, NUSER, x*128, ny*128, smem);
    } else {
      bb -= 314;
      int ny = bb / 40, x = bb - ny*40;
      gemm_nb_body(xm, Wl2, Tm, NMERCH, x*128, ny*128, smem);
    }
  }
}

// ---------------- gather bodies ----------------
__device__ __forceinline__ void gather_body(const u16* __restrict__ XT,
    const int* __restrict__ rp, const int* __restrict__ ss, const float* __restrict__ inv,
    u16* __restrict__ out, int M, int bx){
  int d = bx*4 + (threadIdx.x >> 6);
  if (d >= M) return;
  int lane = threadIdx.x & 63;
  int c = lane << 2;
  float o0=0,o1=0,o2=0,o3=0;
  gather4(XT, ss, rp[d], rp[d+1], lane, c, o0, o1, o2, o3);
  float sc = inv[d];
  ushort4 o; o.x = f2bf(o0*sc); o.y = f2bf(o1*sc); o.z = f2bf(o2*sc); o.w = f2bf(o3*sc);
  *(ushort4*)(out + (size_t)d*HD + c) = o;
}

__device__ __forceinline__ void fused_tx_body(const u16* __restrict__ ACCb,
    const u16* __restrict__ Tu, const u16* __restrict__ Tm,
    const int* __restrict__ rpu, const int* __restrict__ ssu, const float* __restrict__ invu,
    const int* __restrict__ rpm, const int* __restrict__ ssm, const float* __restrict__ invm,
    const float* __restrict__ b0, const float* __restrict__ b2, u16* __restrict__ XT, int M, int bx){
  int d = bx*4 + (threadIdx.x >> 6);
  if (d >= M) return;
  int lane = threadIdx.x & 63;
  int c = lane << 2;
  ushort4 av = *(const ushort4*)(ACCb + (size_t)d*HD + c);
  float r0 = bf2f(av.x), r1 = bf2f(av.y), r2 = bf2f(av.z), r3 = bf2f(av.w);
  {
    float s0=0,s1=0,s2=0,s3=0;
    gather4(Tu, ssu, rpu[d], rpu[d+1], lane, c, s0, s1, s2, s3);
    float sc = invu[d];
    r0 += s0*sc; r1 += s1*sc; r2 += s2*sc; r3 += s3*sc;
  }
  {
    float s0=0,s1=0,s2=0,s3=0;
    gather4(Tm, ssm, rpm[d], rpm[d+1], lane, c, s0, s1, s2, s3);
    float sc = invm[d];
    r0 += s0*sc; r1 += s1*sc; r2 += s2*sc; r3 += s3*sc;
  }
  float4 bb0 = *(const float4*)(b0 + c);
  float4 bb2 = *(const float4*)(b2 + c);
  ushort4 o;
  o.x = f2bf(fmaxf(0.5f*(r0 + bb0.x + bb2.x), 0.f));
  o.y = f2bf(fmaxf(0.5f*(r1 + bb0.y + bb2.y), 0.f));
  o.z = f2bf(fmaxf(0.5f*(r2 + bb0.z + bb2.z), 0.f));
  o.w = f2bf(fmaxf(0.5f*(r3 + bb0.w + bb2.w), 0.f));
  *(ushort4*)(XT + (size_t)d*HD + c) = o;
}

// ---------------- merged B: tm/tu gather-means + fused tx epilogue (homogeneous 28-VGPR bodies) ----
// blocks: [0,1250) tm gather (heavy, deg~80) | [1250,6250) tu gather | [6250,31250) fused_tx
// gathers read XTc (old); fused_tx reads its own ACCb rows and overwrites them in place (row-private).
__global__ __launch_bounds__(256) void gatherB_kernel(const u16* __restrict__ XTc,
    const int* __restrict__ rp_tm, const int* __restrict__ ss_tm, const float* __restrict__ inv_tm, u16* __restrict__ AGGM,
    const int* __restrict__ rp_tu, const int* __restrict__ ss_tu, const float* __restrict__ inv_tu, u16* __restrict__ AGGU,
    u16* __restrict__ ACCb, const u16* __restrict__ Tu, const u16* __restrict__ Tm,
    const int* __restrict__ rp_ut, const int* __restrict__ ss_ut, const float* __restrict__ inv_ut,
    const int* __restrict__ rp_mt, const int* __restrict__ ss_mt, const float* __restrict__ inv_mt,
    const float* __restrict__ b0, const float* __restrict__ b2){
  int b = blockIdx.x;
  if (b < 1250){
    gather_body(XTc, rp_tm, ss_tm, inv_tm, AGGM, NMERCH, b);
  } else if (b < 6250){
    gather_body(XTc, rp_tu, ss_tu, inv_tu, AGGU, NUSER, b - 1250);
  } else {
    fused_tx_body(ACCb, Tu, Tm, rp_ut, ss_ut, inv_ut, rp_mt, ss_mt, inv_mt, b0, b2, ACCb, NTX, b - 6250);
  }
}

// ---------------- batched update GEMM: X_new = bf16(relu(AGG@Wa + Xold@Wb + b)), K=512, staged store ----
__global__ __launch_bounds__(256) void pair_gemm2_kernel(
    const u16* __restrict__ G0, const u16* __restrict__ X0, const u16* __restrict__ Wa0, const u16* __restrict__ Wb0,
    const float* __restrict__ b0, u16* __restrict__ C0, int M0,
    const u16* __restrict__ G1, const u16* __restrict__ X1, const u16* __restrict__ Wa1, const u16* __restrict__ Wb1,
    const float* __restrict__ b1, u16* __restrict__ C1, int M1){
  int z = blockIdx.z;
  const u16* G  = z ? G1 : G0;
  const u16* X  = z ? X1 : X0;
  const u16* Wa = z ? Wa1 : Wa0;
  const u16* Wb = z ? Wb1 : Wb0;
  const float* bias = z ? b1 : b0;
  u16* C = z ? C1 : C0;
  int M = z ? M1 : M0;
  int m0 = blockIdx.x * 128, n0 = blockIdx.y * 128;
  if (m0 >= M) return;
  __shared__ u16 smem[10240];
  u16* As = smem; u16* Bs = smem + 5120;
  int t = threadIdx.x;
  int w = t >> 6, lane = t & 63;
  int wm = (w >> 1) << 6, wn = (w & 1) << 6;
  int lm = lane & 15;
  int lk = (lane >> 4) << 3;
  f32x4 acc[4][4] = {};
  int sr0 = t >> 2, sk0 = (t & 3) << 3;
  int sr1 = sr0 + 64;
  for (int k0 = 0; k0 < 512; k0 += 32){
    const u16* A  = (k0 < 256) ? G : X;
    const u16* WT = (k0 < 256) ? Wa : Wb;
    int kk = k0 & 255;
    uint4 a0 = *(const uint4*)(A  + (size_t)(m0+sr0)*256 + kk + sk0);
    uint4 a1 = *(const uint4*)(A  + (size_t)(m0+sr1)*256 + kk + sk0);
    uint4 b0_ = *(const uint4*)(WT + (size_t)(n0+sr0)*256 + kk + sk0);
    uint4 b1_ = *(const uint4*)(WT + (size_t)(n0+sr1)*256 + kk + sk0);
    *(uint4*)&As[sr0*40 + sk0] = a0;
    *(uint4*)&As[sr1*40 + sk0] = a1;
    *(uint4*)&Bs[sr0*40 + sk0] = b0_;
    *(uint4*)&Bs[sr1*40 + sk0] = b1_;
    __syncthreads();
    bf16x8 af[4], bf[4];
    #pragma unroll
    for (int i = 0; i < 4; ++i) af[i] = *(const bf16x8*)&As[(wm + i*16 + lm)*40 + lk];
    #pragma unroll
    for (int j = 0; j < 4; ++j) bf[j] = *(const bf16x8*)&Bs[(wn + j*16 + lm)*40 + lk];
    #pragma unroll
    for (int i = 0; i < 4; ++i)
      #pragma unroll
      for (int j = 0; j < 4; ++j)
        acc[i][j] = __builtin_amdgcn_mfma_f32_16x16x32_bf16(af[i], bf[j], acc[i][j], 0, 0, 0);
    __syncthreads();
  }
  float bcol[4];
  #pragma unroll
  for (int j = 0; j < 4; ++j) bcol[j] = bias[n0 + wn + j*16 + lm];
  STAGE_STORE(f2bf(fmaxf(acc[i][j][r] + bcol[j], 0.f)))
}

// ---------------- fused head: out = (relu(XT@[Wc1|Wv1]+bH)) @ {Wc2|Wv2} + {bc2|bv2} ----------------
__global__ __launch_bounds__(256) void fused_head_kernel(const u16* __restrict__ A, const u16* __restrict__ BT,
    const float* __restrict__ bias, const float* __restrict__ Wc2, const float* __restrict__ bc2,
    const float* __restrict__ Wv2, const float* __restrict__ bv2, float* __restrict__ out, int M){
  __shared__ u16 As[128*40];
  __shared__ u16 Bs[128*40];
  __shared__ float hpart[128];
  int m0 = blockIdx.x * 128, n0 = blockIdx.y * 128;
  int t = threadIdx.x;
  int w = t >> 6, lane = t & 63;
  int wm = (w >> 1) << 6, wn = (w & 1) << 6;
  int lm = lane & 15;
  int lk = (lane >> 4) << 3;
  if (t < 128) hpart[t] = 0.f;
  f32x4 acc[4][4] = {};
  int sr0 = t >> 2, sk0 = (t & 3) << 3;
  int sr1 = sr0 + 64;
  for (int k0 = 0; k0 < 256; k0 += 32){
    uint4 a0 = *(const uint4*)(A  + (size_t)(m0+sr0)*256 + k0 + sk0);
    uint4 a1 = *(const uint4*)(A  + (size_t)(m0+sr1)*256 + k0 + sk0);
    uint4 b0 = *(const uint4*)(BT + (size_t)(n0+sr0)*256 + k0 + sk0);
    uint4 b1 = *(const uint4*)(BT + (size_t)(n0+sr1)*256 + k0 + sk0);
    *(uint4*)&As[sr0*40 + sk0] = a0;
    *(uint4*)&As[sr1*40 + sk0] = a1;
    *(uint4*)&Bs[sr0*40 + sk0] = b0;
    *(uint4*)&Bs[sr1*40 + sk0] = b1;
    __syncthreads();
    bf16x8 af[4], bf[4];
    #pragma unroll
    for (int i = 0; i < 4; ++i) af[i] = *(const bf16x8*)&As[(wm + i*16 + lm)*40 + lk];
    #pragma unroll
    for (int j = 0; j < 4; ++j) bf[j] = *(const bf16x8*)&Bs[(wn + j*16 + lm)*40 + lk];
    #pragma unroll
    for (int i = 0; i < 4; ++i)
      #pragma unroll
      for (int j = 0; j < 4; ++j)
        acc[i][j] = __builtin_amdgcn_mfma_f32_16x16x32_bf16(af[i], bf[j], acc[i][j], 0, 0, 0);
    __syncthreads();
  }
  const float* w2 = blockIdx.y ? Wv2 : Wc2;
  float badd = blockIdx.y ? bv2[0] : bc2[0];
  size_t outoff = blockIdx.y ? (size_t)M : 0;
  int rsub = (lane >> 4) << 2;
  float w2v[4], bv[4];
  #pragma unroll
  for (int j = 0; j < 4; ++j){
    w2v[j] = w2[wn + j*16 + lm];
    bv[j]  = bias[n0 + wn + j*16 + lm];
  }
  #pragma unroll
  for (int i = 0; i < 4; ++i){
    #pragma unroll
    for (int r = 0; r < 4; ++r){
      float p = 0.f;
      #pragma unroll
      for (int j = 0; j < 4; ++j) p += fmaxf(acc[i][j][r] + bv[j], 0.f) * w2v[j];
      p += __shfl_xor(p, 1); p += __shfl_xor(p, 2);
      p += __shfl_xor(p, 4); p += __shfl_xor(p, 8);
      if (lm == 0) atomicAdd(&hpart[wm + i*16 + rsub + r], p);
    }
  }
  __syncthreads();
  if (t < 128){
    int row = m0 + t;
    if (row < M) out[outoff + row] = hpart[t] + badd;
  }
}

extern "C" void kernel_launch(void* const* d_in, const int* in_sizes, int n_in,
                              void* d_out, int out_size, void* d_ws, size_t ws_size,
                              hipStream_t stream){
  const float* x_tx   = (const float*)d_in[0];
  const float* x_user = (const float*)d_in[1];
  const float* x_merch= (const float*)d_in[2];
  const float* Wp  = (const float*)d_in[3];
  const float* bp  = (const float*)d_in[4];
  const float* Wl  = (const float*)d_in[5];
  const float* bl  = (const float*)d_in[6];
  const float* Wr  = (const float*)d_in[7];
  const float* Wc1 = (const float*)d_in[8];
  const float* bc1 = (const float*)d_in[9];
  const float* Wc2 = (const float*)d_in[10];
  const float* bc2 = (const float*)d_in[11];
  const float* Wv1 = (const float*)d_in[12];
  const float* bv1 = (const float*)d_in[13];
  const float* Wv2 = (const float*)d_in[14];
  const float* bv2 = (const float*)d_in[15];
  const int* e_ut_s = (const int*)d_in[16];
  const int* e_ut_d = (const int*)d_in[17];
  const int* e_tm_s = (const int*)d_in[18];
  const int* e_tm_d = (const int*)d_in[19];
  const int* e_mt_s = (const int*)d_in[20];
  const int* e_mt_d = (const int*)d_in[21];
  const int* e_tu_s = (const int*)d_in[22];
  const int* e_tu_d = (const int*)d_in[23];
  float* out = (float*)d_out;
  const int NE = in_sizes[16];

  // ---- workspace layout (~176 MB) ----
  char* p = (char*)d_ws;
  auto take = [&](size_t bytes)->char*{ char* r = p; p += (bytes + 255) & ~(size_t)255; return r; };
  u16*   XT    = (u16*)  take((size_t)(NTX+ROWPAD)*HD*2);
  u16*   ACCb  = (u16*)  take((size_t)(NTX+ROWPAD)*HD*2);
  u16*   Tu    = (u16*)  take((size_t)NUSER*HD*2);
  u16*   Tm    = (u16*)  take((size_t)NMERCH*HD*2);
  u16*   AGGU  = (u16*)  take((size_t)(NUSER+ROWPAD)*HD*2);
  u16*   AGGM  = (u16*)  take((size_t)(NMERCH+ROWPAD)*HD*2);
  u16*   XU0   = (u16*)  take((size_t)(NUSER+ROWPAD)*HD*2);
  u16*   XU1   = (u16*)  take((size_t)(NUSER+ROWPAD)*HD*2);
  u16*   XM0   = (u16*)  take((size_t)(NMERCH+ROWPAD)*HD*2);
  u16*   XM1   = (u16*)  take((size_t)(NMERCH+ROWPAD)*HD*2);
  float* INV   = (float*)take((size_t)225000*4);
  int*   RP    = (int*)  take((size_t)225008*4);
  int*   SS_ut = (int*)  take((size_t)NE*4);
  int*   SS_tm = (int*)  take((size_t)NE*4);
  int*   SS_mt = (int*)  take((size_t)NE*4);
  int*   SS_tu = (int*)  take((size_t)NE*4);
  int*   PC    = (int*)  take((size_t)4*ECH*64*4);
  int*   PST   = (int*)  take((size_t)4*PSTW*4);
  int*   EB    = (int*)  take((size_t)4*NE*4);
  u16*   WTp   = (u16*)  take((size_t)32*256*2);
  u16*   WTl   = (u16*)  take((size_t)8*65536*2);
  u16*   WTr1  = (u16*)  take((size_t)2*65536*2);
  u16*   WTr3  = (u16*)  take((size_t)2*65536*2);
  u16*   WT02  = (u16*)  take((size_t)2*65536*2);
  u16*   WTH   = (u16*)  take((size_t)65536*2);
  float* bH    = (float*)take((size_t)256*4);

  float* inv_ut = INV,  *inv_tm = INV+100000, *inv_mt = INV+105000, *inv_tu = INV+205000;
  int*   rp_ut  = RP,   *rp_tm  = RP+100001,  *rp_mt  = RP+105002,  *rp_tu  = RP+205003;

  // ---- CSR build: radix partition ----
  csrA_kernel<<<dim3(ECH,4),256,0,stream>>>(e_ut_d, e_tm_d, e_mt_d, e_tu_d, NE, PC);
  csrB_kernel<<<dim3(1,4),64,0,stream>>>(PC, PST, RP, NE);
  csrC_kernel<<<dim3(ECH,4),256,0,stream>>>(e_ut_s, e_ut_d, e_tm_s, e_tm_d, e_mt_s, e_mt_d,
      e_tu_s, e_tu_d, PC, EB, NE);
  csrD_kernel<<<dim3(49,4),256,0,stream>>>(EB, PST, RP, INV, SS_ut, SS_tm, SS_mt, SS_tu, NE);

  // ---- weight prep ----
  wprep_kernel<<<dim3(256,16),256,0,stream>>>(Wl, Wr, Wp, Wc1, Wv1, bc1, bv1,
      WTl, WTr1, WTr3, WT02, WTH, WTp, bH);

  // ---- init activations ----
  cvt2_kernel<<<dim3(5000,2),256,0,stream>>>(x_user, x_merch, XU0, XM0);
  proj_gemm_kernel<<<dim3(782,2),256,0,stream>>>(x_tx, WTp, bp, XT, NTX);

  u16* xt_cur  = XT;   u16* acc_buf = ACCb;   // ping-pong: fused_tx writes acc_buf in place
  u16* xu_cur = XU0; u16* xu_nxt = XU1;
  u16* xm_cur = XM0; u16* xm_nxt = XM1;

  for (int l = 0; l < 2; ++l){
    const float* bl_l = bl + (size_t)l*4*256;
    u16* WTl_l = WTl + (size_t)l*4*65536;

    // A: all GEMMs reading old state (root -> acc_buf, transforms -> Tu/Tm), one launch
    gemmsA_kernel<<<1958,256,0,stream>>>(
        xt_cur, WT02 + (size_t)l*65536, acc_buf,
        xu_cur, WTl_l + 0*65536, Tu,
        xm_cur, WTl_l + 2*65536, Tm);

    // B: all gathers, one launch. tm/tu gathers read xt_cur; fused_tx finalizes acc_buf rows
    // in place (row-private read-then-write) -> acc_buf becomes the NEW tx state.
    gatherB_kernel<<<31250,256,0,stream>>>(xt_cur,
        rp_tm, SS_tm, inv_tm, AGGM,
        rp_tu, SS_tu, inv_tu, AGGU,
        acc_buf, Tu, Tm,
        rp_ut, SS_ut, inv_ut, rp_mt, SS_mt, inv_mt,
        bl_l + 0*256, bl_l + 2*256);
    { u16* tmp = xt_cur; xt_cur = acc_buf; acc_buf = tmp; }

    // C: user/merchant updates (batched, virtual K=512, fused bias+relu+bf16, staged store)
    pair_gemm2_kernel<<<dim3(157,2,2),256,0,stream>>>(
        AGGU, xu_cur, WTl_l + 3*65536, WTr3 + (size_t)l*65536, bl_l + 3*256, xu_nxt, NUSER,
        AGGM, xm_cur, WTl_l + 1*65536, WTr1 + (size_t)l*65536, bl_l + 1*256, xm_nxt, NMERCH);

    { u16* tmp = xu_cur; xu_cur = xu_nxt; xu_nxt = tmp; }
    { u16* tmp = xm_cur; xm_cur = xm_nxt; xm_nxt = tmp; }
  }

  // fused heads (direct out write)
  fused_head_kernel<<<dim3(782,2),256,0,stream>>>(xt_cur, WTH, bH, Wc2, bc2, Wv2, bv2, out, NTX);
}